// Round 9
// baseline (261.127 us; speedup 1.0000x reference)
//
#include <hip/hip_runtime.h>
#include <hip/hip_bf16.h>
#include <cstdint>

#define BB   8
#define CCH  128
#define NND  16
#define HWD  3136      // 56*56
#define LLT  50176     // 16*3136
#define HWB  32        // hw columns per k1 block (fallback); 3136 = 98*32
#define NHB  98
#define K3WB 64        // hw columns per k3 block; 3136 = 49*64
#define K3NB 49

// ---- fallback workspace layout (float offsets) ----
#define OFF_SP  0                         // 8*98*16384  per-block Gram partials
#define OFF_RP  12845056                  // 8*98*128    per-block rowsum partials
#define OFF_S   12945408                  // 8*16384     reduced Gram
#define OFF_M   13076480
#define OFF_Q   13207552
#define OFF_AV  13338624
#define OFF_CV  13339648

// ---- two-pass workspace layout (float offsets) ----
#define OFF2_XPH 0                        // 8*6272*128*8 bf16 (as 25,690,112 floats)
#define OFF2_XPL 25690112
#define OFF2_S   51380224                 // 8*16384 (atomics, zeroed by kT)
#define OFF2_R   51511296                 // 8*128   (atomics, zeroed by kT)
#define OFF2_M   51512320
#define OFF2_Q   51643392
#define OFF2_AV  51774464
#define OFF2_CV  51775488
#define NEED2_BYTES ((size_t)51776512*4)

typedef __attribute__((ext_vector_type(8)))  short bf16x8;
typedef __attribute__((ext_vector_type(16))) float f32x16;

__device__ __forceinline__ uint32_t fbits(float f){ union{float f;uint32_t u;}v; v.f=f; return v.u; }
__device__ __forceinline__ float bitsf(uint32_t u){ union{uint32_t u;float f;}v; v.u=u; return v.f; }
__device__ __forceinline__ float bf2f(unsigned short u){ return bitsf(((uint32_t)u)<<16); }

#define MFMA32(a,b,c) __builtin_amdgcn_mfma_f32_32x32x16_bf16((a),(b),(c),0,0,0)

#define BARRIER_KEEP_VMEM() do{                                  \
    asm volatile("s_waitcnt lgkmcnt(0)" ::: "memory");           \
    __builtin_amdgcn_s_barrier();                                \
  }while(0)

// ============================ TWO-PASS PATH =================================

// kT_pack: transpose + hi/lo split. block = (b, cg of 32ch, n). 512 blocks.
// Reads: per-channel sequential. Writes: 512-B chunks, row-sequential.
// Also zeroes S and r (atomic accumulators for kG_stream).
__global__ __launch_bounds__(256,2) void kT_pack(const float* __restrict__ x,
    unsigned short* __restrict__ xPh, unsigned short* __restrict__ xPl,
    float* __restrict__ S, float* __restrict__ r)
{
  __shared__ __align__(16) unsigned short sh[28*33*8];   // padded stride 33
  __shared__ __align__(16) unsigned short sl[28*33*8];
  const int blk = blockIdx.x;
  const int n  = blk & 15;
  const int cg = (blk >> 4) & 3;
  const int b  = blk >> 6;
  const int tid = threadIdx.x;
  const int cl = tid >> 3;          // local channel 0..31
  const int p  = tid & 7;           // float4 piece

  // zero the atomic accumulators: 512 blocks x 256 floats == 131072 = |S|
  S[blk*256 + tid] = 0.f;
  if(blk < 4) r[blk*256 + tid] = 0.f;

  const float* xr = x + (size_t)(b*CCH + cg*32 + cl)*LLT + n*HWD;

  float4 v[7];
  #pragma unroll
  for(int s=0;s<7;s++) v[s] = *(const float4*)(xr + 4*p + 32*s);   // tile 0

  for(int t=0; t<14; t++){
    // convert tile t (held in v) into LDS
    #pragma unroll
    for(int s=0;s<7;s++){
      const float x0=v[s].x, x1=v[s].y, x2=v[s].z, x3=v[s].w;
      const uint32_t a0=fbits(x0),a1=fbits(x1),a2=fbits(x2),a3=fbits(x3);
      const int h0 = __builtin_amdgcn_perm(a1, a0, 0x07060302u);
      const int h1 = __builtin_amdgcn_perm(a3, a2, 0x07060302u);
      const float l0 = x0 - bitsf(a0&0xFFFF0000u);
      const float l1 = x1 - bitsf(a1&0xFFFF0000u);
      const float l2 = x2 - bitsf(a2&0xFFFF0000u);
      const float l3 = x3 - bitsf(a3&0xFFFF0000u);
      const int g0 = __builtin_amdgcn_perm(fbits(l1), fbits(l0), 0x07060302u);
      const int g1 = __builtin_amdgcn_perm(fbits(l3), fbits(l2), 0x07060302u);
      const int lcl = (p>>1) + 4*s;                 // 0..27
      const int sa = (lcl*33 + cl)*8 + 4*(p&1);
      *(int2*)&sh[sa] = make_int2(h0,h1);
      *(int2*)&sl[sa] = make_int2(g0,g1);
    }
    BARRIER_KEEP_VMEM();
    if(t+1 < 14){                                    // prefetch next tile
      #pragma unroll
      for(int s=0;s<7;s++) v[s] = *(const float4*)(xr + 224*(t+1) + 4*p + 32*s);
    }
    // write out: 28 rows x 32c x 16B for hi and lo (1792 pieces / 7 per thread)
    #pragma unroll
    for(int i=0;i<7;i++){
      const int pc = i*256 + tid;
      const int c  = pc & 31;
      const int rr = pc >> 5;                        // 0..55
      const int lcl = (rr<28) ? rr : rr-28;
      const size_t go = ((size_t)(b*6272 + n*392 + 28*t + lcl)*128 + cg*32 + c)*8;
      const int4 val = *(const int4*)&((rr<28)? sh : sl)[(lcl*33 + c)*8];
      if(rr<28) *(int4*)&xPh[go] = val;
      else      *(int4*)&xPl[go] = val;
    }
    BARRIER_KEEP_VMEM();
  }
}

// kG_stream: Gram + Y + rowsum, streaming from xP. block = (b, j' of 98).
// No LDS, no barriers; fragments load directly (8-KB contiguous runs).
__global__ __launch_bounds__(256,3) void kG_stream(
    const unsigned short* __restrict__ xPh, const unsigned short* __restrict__ xPl,
    float* __restrict__ S, float* __restrict__ r, float* __restrict__ Y)
{
  const int jp = blockIdx.x % 98;       // hw8-range [4jp, 4jp+4)
  const int b  = blockIdx.x / 98;
  const int tid = threadIdx.x, lane = tid & 63, w = tid >> 6;
  const int wr = w >> 1, wc = w & 1;
  const int hh = lane >> 5, cli = lane & 31;

  f32x16 acc[2][2];
  #pragma unroll
  for(int ai=0;ai<2;ai++)
    #pragma unroll
    for(int bi=0;bi<2;bi++)
      #pragma unroll
      for(int e=0;e<16;e++) acc[ai][bi][e] = 0.f;
  float yac[2][8];
  #pragma unroll
  for(int q=0;q<2;q++)
    #pragma unroll
    for(int e=0;e<8;e++) yac[q][e] = 0.f;

  const size_t base = (size_t)b*6272*1024;
  for(int n=0;n<NND;n++){
    const size_t rb = base + (size_t)(n*392 + 4*jp)*1024;
    #pragma unroll
    for(int qp=0;qp<2;qp++){
      const size_t r0 = rb + (size_t)(2*qp + hh)*1024;
      const bf16x8 a0h = *(const bf16x8*)&xPh[r0 + (64*wr      + cli)*8];
      const bf16x8 a0l = *(const bf16x8*)&xPl[r0 + (64*wr      + cli)*8];
      const bf16x8 a1h = *(const bf16x8*)&xPh[r0 + (64*wr + 32 + cli)*8];
      const bf16x8 a1l = *(const bf16x8*)&xPl[r0 + (64*wr + 32 + cli)*8];
      const bf16x8 b0h = *(const bf16x8*)&xPh[r0 + (64*wc      + cli)*8];
      const bf16x8 b0l = *(const bf16x8*)&xPl[r0 + (64*wc      + cli)*8];
      const bf16x8 b1h = *(const bf16x8*)&xPh[r0 + (64*wc + 32 + cli)*8];
      const bf16x8 b1l = *(const bf16x8*)&xPl[r0 + (64*wc + 32 + cli)*8];
      acc[0][0] = MFMA32(a0h, b0h, acc[0][0]);
      acc[0][0] = MFMA32(a0h, b0l, acc[0][0]);
      acc[0][0] = MFMA32(a0l, b0h, acc[0][0]);
      acc[0][1] = MFMA32(a0h, b1h, acc[0][1]);
      acc[0][1] = MFMA32(a0h, b1l, acc[0][1]);
      acc[0][1] = MFMA32(a0l, b1h, acc[0][1]);
      acc[1][0] = MFMA32(a1h, b0h, acc[1][0]);
      acc[1][0] = MFMA32(a1h, b0l, acc[1][0]);
      acc[1][0] = MFMA32(a1l, b0h, acc[1][0]);
      acc[1][1] = MFMA32(a1h, b1h, acc[1][1]);
      acc[1][1] = MFMA32(a1h, b1l, acc[1][1]);
      acc[1][1] = MFMA32(a1l, b1h, acc[1][1]);
      // Y/r side-product: channels 64wr+32wc+cli come from a(wc) fragments
      const bf16x8 ych = wc ? a1h : a0h;
      const bf16x8 ycl = wc ? a1l : a0l;
      #pragma unroll
      for(int e=0;e<8;e++)
        yac[qp][e] += bf2f((unsigned short)ych[e]) + bf2f((unsigned short)ycl[e]);
    }
  }

  // Y write (exclusive ownership: hw 32jp..32jp+31, c = 64wr+32wc+cli)
  const int c = 64*wr + 32*wc + cli;
  #pragma unroll
  for(int qp=0;qp<2;qp++){
    const int hw = (4*jp + 2*qp + hh)*8;
    float4 o0 = make_float4(yac[qp][0]*0.0625f, yac[qp][1]*0.0625f,
                            yac[qp][2]*0.0625f, yac[qp][3]*0.0625f);
    float4 o1 = make_float4(yac[qp][4]*0.0625f, yac[qp][5]*0.0625f,
                            yac[qp][6]*0.0625f, yac[qp][7]*0.0625f);
    *(float4*)(Y + ((size_t)b*CCH + c)*HWD + hw    ) = o0;
    *(float4*)(Y + ((size_t)b*CCH + c)*HWD + hw + 4) = o1;
  }
  // rowsum: pair the two hh-halves then one atomic per (block, c)
  float rs = 0.f;
  #pragma unroll
  for(int qp=0;qp<2;qp++)
    #pragma unroll
    for(int e=0;e<8;e++) rs += yac[qp][e];
  rs += __shfl_xor(rs, 32);
  if(hh==0) atomicAdd(&r[b*CCH + c], rs);

  // Gram accumulate (atomics; zeroed by kT_pack)
  float* Sb = S + (size_t)b*CCH*CCH;
  const int roff = 4*hh;
  #pragma unroll
  for(int ai=0;ai<2;ai++)
    #pragma unroll
    for(int bi=0;bi<2;bi++)
      #pragma unroll
      for(int reg=0;reg<16;reg++){
        const int row = 64*wr + 32*ai + roff + (reg&3) + 8*(reg>>2);
        atomicAdd(&Sb[(size_t)row*CCH + 64*wc + 32*bi + cli], acc[ai][bi][reg]);
      }
}

// ============================ FALLBACK PATH =================================

__global__ __launch_bounds__(256,3) void k1_gram(const float* __restrict__ x,
    float* __restrict__ Sp, float* __restrict__ rp, float* __restrict__ Y)
{
  __shared__ __align__(16) short lds_h[2][4*129*8];
  __shared__ __align__(16) short lds_l[2][4*129*8];
  const int b   = blockIdx.x / NHB;
  const int hb  = blockIdx.x % NHB;
  const int hw0 = hb * HWB;
  const int tid = threadIdx.x;
  const int lane = tid & 63, w = tid >> 6;
  const int wr = w >> 1, wc = w & 1;
  const int cr = tid >> 3;
  const int p  = tid & 7;
  const int kc = p >> 1, hf = p & 1;
  const float* xb = x + (size_t)b*CCH*LLT + (size_t)cr*LLT + hw0 + 4*p;

  f32x16 acc[2][2];
  #pragma unroll
  for(int ai=0;ai<2;ai++)
    #pragma unroll
    for(int bi=0;bi<2;bi++)
      #pragma unroll
      for(int e=0;e<16;e++) acc[ai][bi][e] = 0.f;
  float yac[16];
  #pragma unroll
  for(int i=0;i<16;i++) yac[i]=0.f;

  float4 vA[4], vB[4];

#define LOADP(VV, nn)                                                       \
  { _Pragma("unroll")                                                       \
    for(int j=0;j<4;j++)                                                    \
      VV[j] = *(const float4*)(xb + (size_t)(32*j)*LLT + (size_t)(nn)*HWD); }

#define SPLIT(bufi, VV)                                                     \
  {                                                                         \
    _Pragma("unroll")                                                       \
    for(int j=0;j<4;j++){                                                   \
      const int c = 32*j + cr;                                              \
      const float x0=VV[j].x, x1=VV[j].y, x2=VV[j].z, x3=VV[j].w;           \
      const uint32_t a0=fbits(x0),a1=fbits(x1),a2=fbits(x2),a3=fbits(x3);   \
      const int h0 = __builtin_amdgcn_perm(a1, a0, 0x07060302u);            \
      const int h1 = __builtin_amdgcn_perm(a3, a2, 0x07060302u);            \
      const float l0 = x0 - bitsf(a0&0xFFFF0000u);                          \
      const float l1 = x1 - bitsf(a1&0xFFFF0000u);                          \
      const float l2 = x2 - bitsf(a2&0xFFFF0000u);                          \
      const float l3 = x3 - bitsf(a3&0xFFFF0000u);                          \
      const int g0 = __builtin_amdgcn_perm(fbits(l1), fbits(l0), 0x07060302u); \
      const int g1 = __builtin_amdgcn_perm(fbits(l3), fbits(l2), 0x07060302u); \
      const int sa = (kc*129 + c)*8 + 4*hf;                                 \
      *(int2*)&lds_h[bufi][sa] = make_int2(h0,h1);                          \
      *(int2*)&lds_l[bufi][sa] = make_int2(g0,g1);                          \
      yac[4*j+0]+=x0; yac[4*j+1]+=x1; yac[4*j+2]+=x2; yac[4*j+3]+=x3;       \
    }                                                                       \
  }

#define COMPUTE(bufi)                                                       \
  { _Pragma("unroll")                                                       \
    for(int ks=0;ks<2;ks++){                                                \
      const int kk = 2*ks + (lane>>5);                                      \
      const int rbase = (kk*129 + (lane&31))*8;                             \
      const bf16x8 a0h = *(const bf16x8*)&lds_h[bufi][rbase + (64*wr    )*8]; \
      const bf16x8 a0l = *(const bf16x8*)&lds_l[bufi][rbase + (64*wr    )*8]; \
      const bf16x8 a1h = *(const bf16x8*)&lds_h[bufi][rbase + (64*wr+32)*8]; \
      const bf16x8 a1l = *(const bf16x8*)&lds_l[bufi][rbase + (64*wr+32)*8]; \
      const bf16x8 b0h = *(const bf16x8*)&lds_h[bufi][rbase + (64*wc    )*8]; \
      const bf16x8 b0l = *(const bf16x8*)&lds_l[bufi][rbase + (64*wc    )*8]; \
      const bf16x8 b1h = *(const bf16x8*)&lds_h[bufi][rbase + (64*wc+32)*8]; \
      const bf16x8 b1l = *(const bf16x8*)&lds_l[bufi][rbase + (64*wc+32)*8]; \
      acc[0][0] = MFMA32(a0h, b0h, acc[0][0]);                              \
      acc[0][0] = MFMA32(a0h, b0l, acc[0][0]);                              \
      acc[0][0] = MFMA32(a0l, b0h, acc[0][0]);                              \
      acc[0][1] = MFMA32(a0h, b1h, acc[0][1]);                              \
      acc[0][1] = MFMA32(a0h, b1l, acc[0][1]);                              \
      acc[0][1] = MFMA32(a0l, b1h, acc[0][1]);                              \
      acc[1][0] = MFMA32(a1h, b0h, acc[1][0]);                              \
      acc[1][0] = MFMA32(a1h, b0l, acc[1][0]);                              \
      acc[1][0] = MFMA32(a1l, b0h, acc[1][0]);                              \
      acc[1][1] = MFMA32(a1h, b1h, acc[1][1]);                              \
      acc[1][1] = MFMA32(a1h, b1l, acc[1][1]);                              \
      acc[1][1] = MFMA32(a1l, b1h, acc[1][1]);                              \
    } }

  LOADP(vA, 0);
  LOADP(vB, 1);
  SPLIT(0, vA);
  LOADP(vA, 2);
  BARRIER_KEEP_VMEM();

  for(int n2=0;n2<NND/2;n2++){
    const int n = 2*n2;
    COMPUTE(0);
    SPLIT(1, vB);
    if(n+3<NND) LOADP(vB, n+3);
    BARRIER_KEEP_VMEM();
    COMPUTE(1);
    if(n+2<NND){
      SPLIT(0, vA);
      if(n+4<NND) LOADP(vA, n+4);
    }
    BARRIER_KEEP_VMEM();
  }
#undef COMPUTE
#undef SPLIT
#undef LOADP

  #pragma unroll
  for(int j=0;j<4;j++){
    float4 o4 = make_float4(yac[4*j]*0.0625f, yac[4*j+1]*0.0625f,
                            yac[4*j+2]*0.0625f, yac[4*j+3]*0.0625f);
    *(float4*)(Y + ((size_t)b*CCH + 32*j + cr)*HWD + hw0 + 4*p) = o4;
  }
  #pragma unroll
  for(int j=0;j<4;j++){
    float s = yac[4*j]+yac[4*j+1]+yac[4*j+2]+yac[4*j+3];
    #pragma unroll
    for(int st=1;st<8;st<<=1) s += __shfl_xor(s, st, 8);
    if(p==0) rp[(size_t)(b*NHB+hb)*CCH + 32*j + cr] = s;
  }

  float* Sb = Sp + (size_t)(b*NHB+hb)*CCH*CCH;
  const int col = lane & 31, roff = 4*(lane>>5);
  #pragma unroll
  for(int ai=0;ai<2;ai++)
    #pragma unroll
    for(int bi=0;bi<2;bi++)
      #pragma unroll
      for(int reg=0;reg<16;reg++){
        const int row = 64*wr + 32*ai + roff + (reg&3) + 8*(reg>>2);
        Sb[(size_t)row*CCH + 64*wc + 32*bi + col] = acc[ai][bi][reg];
      }
}

__global__ __launch_bounds__(256) void k1r(const float* __restrict__ Sp,
                                           float* __restrict__ S, int nparts)
{
  const int b  = blockIdx.x >> 4;
  const int ch = blockIdx.x & 15;
  const int i  = ch*1024 + threadIdx.x*4;
  const float* p = Sp + (size_t)b*nparts*CCH*CCH + i;
  float4 s = make_float4(0.f,0.f,0.f,0.f);
  for(int hb=0;hb<nparts;hb++){
    float4 v = *(const float4*)(p + (size_t)hb*CCH*CCH);
    s.x+=v.x; s.y+=v.y; s.z+=v.z; s.w+=v.w;
  }
  *(float4*)(S + (size_t)b*CCH*CCH + i) = s;
}

// ====================== SHARED TAIL (both paths) ============================

__global__ __launch_bounds__(256) void k2ab(const float* __restrict__ S, const float* __restrict__ rp,
    const float* __restrict__ wq, const float* __restrict__ bq,
    const float* __restrict__ wk, const float* __restrict__ bk,
    const float* __restrict__ wv, const float* __restrict__ bv,
    float* __restrict__ M, float* __restrict__ av, int nparts)
{
  __shared__ __align__(16) float t1[16][132];
  __shared__ float rb_s[CCH];
  __shared__ float wrk_s[CCH];
  __shared__ float wrq_s[16];
  const int b   = blockIdx.x >> 3;
  const int r0  = (blockIdx.x & 7) * 16;
  const int tid = threadIdx.x;
  const float* Sb = S + (size_t)b*CCH*CCH;

  if(tid < CCH){
    float s = 0.f;
    const float* rpb = rp + (size_t)b*nparts*CCH + tid;
    for(int hb=0;hb<nparts;hb++) s += rpb[hb*CCH];
    rb_s[tid] = s;
  }
  __syncthreads();

  if(tid < CCH){
    float s = 0.f;
    for(int m=0;m<CCH;m++) s += wk[(size_t)tid*CCH+m]*rb_s[m];
    wrk_s[tid] = s;
  } else if(tid < CCH+16){
    const int rr2 = tid - CCH;
    float s = 0.f;
    for(int m=0;m<CCH;m++) s += wq[(size_t)(r0+rr2)*CCH+m]*rb_s[m];
    wrq_s[rr2] = s;
  }

  const int rr = tid >> 4;
  const int c0 = (tid & 15) * 8;
  {
    float a8[8] = {0,0,0,0,0,0,0,0};
    const float* wqr = wq + (size_t)(r0+rr)*CCH;
    for(int m4=0;m4<32;m4++){
      float4 w4 = *(const float4*)(wqr + 4*m4);
      const float wl[4] = {w4.x,w4.y,w4.z,w4.w};
      #pragma unroll
      for(int mm=0;mm<4;mm++){
        const int m = 4*m4+mm;
        const float w = wl[mm];
        float4 s0 = *(const float4*)(Sb + (size_t)m*CCH + c0);
        float4 s1 = *(const float4*)(Sb + (size_t)m*CCH + c0 + 4);
        a8[0]=fmaf(w,s0.x,a8[0]); a8[1]=fmaf(w,s0.y,a8[1]);
        a8[2]=fmaf(w,s0.z,a8[2]); a8[3]=fmaf(w,s0.w,a8[3]);
        a8[4]=fmaf(w,s1.x,a8[4]); a8[5]=fmaf(w,s1.y,a8[5]);
        a8[6]=fmaf(w,s1.z,a8[6]); a8[7]=fmaf(w,s1.w,a8[7]);
      }
    }
    #pragma unroll
    for(int j=0;j<8;j++) t1[rr][c0+j] = a8[j];
  }
  __syncthreads();

  const int j0 = c0;
  float g[8] = {0,0,0,0,0,0,0,0};
  for(int c4=0;c4<32;c4++){
    float4 tv = *(const float4*)(&t1[rr][4*c4]);
    #pragma unroll
    for(int jj=0;jj<8;jj++){
      float4 w4 = *(const float4*)(wk + (size_t)(j0+jj)*CCH + 4*c4);
      g[jj]=fmaf(tv.x,w4.x,g[jj]); g[jj]=fmaf(tv.y,w4.y,g[jj]);
      g[jj]=fmaf(tv.z,w4.z,g[jj]); g[jj]=fmaf(tv.w,w4.w,g[jj]);
    }
  }
  const float bqr  = bq[r0+rr];
  const float wrqr = wrq_s[rr];
  #pragma unroll
  for(int jj=0;jj<8;jj++)
    g[jj] += wrqr*bk[j0+jj] + bqr*wrk_s[j0+jj] + (float)LLT*bqr*bk[j0+jj];

  float mx = g[0];
  #pragma unroll
  for(int jj=1;jj<8;jj++) mx = fmaxf(mx, g[jj]);
  #pragma unroll
  for(int s=1;s<16;s<<=1) mx = fmaxf(mx, __shfl_xor(mx, s, 16));
  float ex[8], sum=0.f;
  #pragma unroll
  for(int jj=0;jj<8;jj++){ ex[jj] = expf(g[jj]-mx); sum += ex[jj]; }
  #pragma unroll
  for(int s=1;s<16;s<<=1) sum += __shfl_xor(sum, s, 16);
  const float inv = 1.0f/sum;

  float pa = 0.f;
  #pragma unroll
  for(int jj=0;jj<8;jj++) pa += ex[jj]*inv*bv[j0+jj];
  #pragma unroll
  for(int s=1;s<16;s<<=1) pa += __shfl_xor(pa, s, 16);
  if((tid&15)==0) av[b*CCH + r0+rr] = pa;

  __syncthreads();
  #pragma unroll
  for(int jj=0;jj<8;jj++) t1[rr][j0+jj] = ex[jj]*inv;
  __syncthreads();

  {
    float a8[8] = {0,0,0,0,0,0,0,0};
    for(int k4=0;k4<32;k4++){
      float4 a4 = *(const float4*)(&t1[rr][4*k4]);
      const float al[4] = {a4.x,a4.y,a4.z,a4.w};
      #pragma unroll
      for(int kk=0;kk<4;kk++){
        const int k = 4*k4+kk;
        const float wgt = al[kk];
        float4 v0 = *(const float4*)(wv + (size_t)k*CCH + c0);
        float4 v1 = *(const float4*)(wv + (size_t)k*CCH + c0 + 4);
        a8[0]=fmaf(wgt,v0.x,a8[0]); a8[1]=fmaf(wgt,v0.y,a8[1]);
        a8[2]=fmaf(wgt,v0.z,a8[2]); a8[3]=fmaf(wgt,v0.w,a8[3]);
        a8[4]=fmaf(wgt,v1.x,a8[4]); a8[5]=fmaf(wgt,v1.y,a8[5]);
        a8[6]=fmaf(wgt,v1.z,a8[6]); a8[7]=fmaf(wgt,v1.w,a8[7]);
      }
    }
    float* Mr = M + ((size_t)b*CCH + r0+rr)*CCH + c0;
    *(float4*)(Mr  ) = make_float4(a8[0],a8[1],a8[2],a8[3]);
    *(float4*)(Mr+4) = make_float4(a8[4],a8[5],a8[6],a8[7]);
  }
}

__global__ __launch_bounds__(256) void k2c(const float* __restrict__ M,
    const float* __restrict__ wo, const float* __restrict__ bo,
    const float* __restrict__ av, float* __restrict__ Q, float* __restrict__ cv)
{
  const int b  = blockIdx.x >> 3;
  const int o0 = (blockIdx.x & 7)*16;
  const int tid = threadIdx.x;
  const int rr = tid>>4, c0 = (tid&15)*8;
  const int o  = o0 + rr;
  const float* wor = wo + (size_t)o*CCH;
  const float* Mb  = M + (size_t)b*CCH*CCH;
  float a8[8] = {0,0,0,0,0,0,0,0};
  for(int m4=0;m4<32;m4++){
    float4 w4 = *(const float4*)(wor + 4*m4);
    const float wl[4] = {w4.x,w4.y,w4.z,w4.w};
    #pragma unroll
    for(int mm=0;mm<4;mm++){
      const int m = 4*m4+mm;
      const float w = wl[mm];
      float4 v0 = *(const float4*)(Mb + (size_t)m*CCH + c0);
      float4 v1 = *(const float4*)(Mb + (size_t)m*CCH + c0 + 4);
      a8[0]=fmaf(w,v0.x,a8[0]); a8[1]=fmaf(w,v0.y,a8[1]);
      a8[2]=fmaf(w,v0.z,a8[2]); a8[3]=fmaf(w,v0.w,a8[3]);
      a8[4]=fmaf(w,v1.x,a8[4]); a8[5]=fmaf(w,v1.y,a8[5]);
      a8[6]=fmaf(w,v1.z,a8[6]); a8[7]=fmaf(w,v1.w,a8[7]);
    }
  }
  #pragma unroll
  for(int j=0;j<8;j++) if(o == c0+j) a8[j] += 1.0f;
  float* Qr = Q + ((size_t)b*CCH + o)*CCH + c0;
  *(float4*)(Qr  ) = make_float4(a8[0],a8[1],a8[2],a8[3]);
  *(float4*)(Qr+4) = make_float4(a8[4],a8[5],a8[6],a8[7]);

  if(tid < 16){
    const int oo = o0 + tid;
    float s = 0.f;
    for(int m=0;m<CCH;m++) s += wo[(size_t)oo*CCH+m]*av[b*CCH+m];
    cv[b*CCH + oo] = s + bo[oo];
  }
}

__global__ __launch_bounds__(256,2) void k3(const float* __restrict__ Q,
    const float* __restrict__ cv, float* __restrict__ out)
{
  __shared__ __align__(16) float4 qs[4096];
  const int b   = blockIdx.x / K3NB;
  const int hb  = blockIdx.x % K3NB;
  const int hw0 = hb * K3WB;
  const int tid = threadIdx.x;

  const float4* Qg = (const float4*)(Q + (size_t)b*CCH*CCH);
  #pragma unroll
  for(int it=0; it<16; it++){
    const int idx = it*256 + tid;
    const int row = idx >> 5, ch = idx & 31;
    qs[(row<<5) | (ch ^ (row>>3))] = Qg[idx];
  }
  __syncthreads();

  const int tx = tid & 15, ty = tid >> 4;
  const int o0 = tx*8;
  const int hg = ty*4;
  float acc[8][4];
  #pragma unroll
  for(int i=0;i<8;i++){ acc[i][0]=0.f; acc[i][1]=0.f; acc[i][2]=0.f; acc[i][3]=0.f; }

  const float* Yb = out + (size_t)b*CCH*HWD + hw0 + hg;
  for(int c4=0;c4<32;c4++){
    float4 yv[4];
    #pragma unroll
    for(int mm=0;mm<4;mm++) yv[mm] = *(const float4*)(Yb + (size_t)(4*c4+mm)*HWD);
    #pragma unroll
    for(int i=0;i<8;i++){
      const int row = o0 + i;
      const float4 q4 = qs[(row<<5) | (c4 ^ tx)];
      const float ql[4] = {q4.x,q4.y,q4.z,q4.w};
      #pragma unroll
      for(int mm=0;mm<4;mm++){
        acc[i][0]=fmaf(ql[mm],yv[mm].x,acc[i][0]);
        acc[i][1]=fmaf(ql[mm],yv[mm].y,acc[i][1]);
        acc[i][2]=fmaf(ql[mm],yv[mm].z,acc[i][2]);
        acc[i][3]=fmaf(ql[mm],yv[mm].w,acc[i][3]);
      }
    }
  }
  __syncthreads();
  #pragma unroll
  for(int i=0;i<8;i++){
    const float c = cv[b*CCH + o0+i];
    float4 o4 = make_float4(acc[i][0]+c, acc[i][1]+c, acc[i][2]+c, acc[i][3]+c);
    *(float4*)(out + ((size_t)b*CCH + o0+i)*HWD + hw0 + hg) = o4;
  }
}

extern "C" void kernel_launch(void* const* d_in, const int* in_sizes, int n_in,
                              void* d_out, int out_size, void* d_ws, size_t ws_size,
                              hipStream_t stream) {
  const float* x  = (const float*)d_in[0];
  const float* wq = (const float*)d_in[1];
  const float* bq = (const float*)d_in[2];
  const float* wk = (const float*)d_in[3];
  const float* bk = (const float*)d_in[4];
  const float* wv = (const float*)d_in[5];
  const float* bv = (const float*)d_in[6];
  const float* wo = (const float*)d_in[7];
  const float* bo = (const float*)d_in[8];
  float* out = (float*)d_out;
  float* ws  = (float*)d_ws;

  if(ws_size >= NEED2_BYTES){
    // two-pass path: transpose+split, then streaming Gram (no fills, no k1r)
    unsigned short* xph = (unsigned short*)(ws + OFF2_XPH);
    unsigned short* xpl = (unsigned short*)(ws + OFF2_XPL);
    kT_pack  <<<512, 256, 0, stream>>>(x, xph, xpl, ws+OFF2_S, ws+OFF2_R);
    kG_stream<<<8*98, 256, 0, stream>>>(xph, xpl, ws+OFF2_S, ws+OFF2_R, out);
    k2ab<<<64, 256, 0, stream>>>(ws+OFF2_S, ws+OFF2_R, wq, bq, wk, bk, wv, bv,
                                 ws+OFF2_M, ws+OFF2_AV, 1);
    k2c <<<64, 256, 0, stream>>>(ws+OFF2_M, wo, bo, ws+OFF2_AV, ws+OFF2_Q, ws+OFF2_CV);
    k3  <<<BB*K3NB, 256, 0, stream>>>(ws+OFF2_Q, ws+OFF2_CV, out);
  } else {
    // fallback: prior single-pass path
    k1_gram<<<BB*NHB, 256, 0, stream>>>(x, ws+OFF_SP, ws+OFF_RP, out);
    k1r<<<128, 256, 0, stream>>>(ws+OFF_SP, ws+OFF_S, NHB);
    k2ab<<<64, 256, 0, stream>>>(ws+OFF_S, ws+OFF_RP, wq, bq, wk, bk, wv, bv,
                                 ws+OFF_M, ws+OFF_AV, NHB);
    k2c<<<64, 256, 0, stream>>>(ws+OFF_M, wo, bo, ws+OFF_AV, ws+OFF_Q, ws+OFF_CV);
    k3<<<BB*K3NB, 256, 0, stream>>>(ws+OFF_Q, ws+OFF_CV, out);
  }
}

// Round 10
// 187.589 us; speedup vs baseline: 1.3920x; 1.3920x over previous
//
#include <hip/hip_runtime.h>
#include <hip/hip_bf16.h>
#include <cstdint>

#define BB   8
#define CCH  128
#define NND  16
#define HWD  3136      // 56*56
#define LLT  50176     // 16*3136
#define HWB  32        // hw columns per k1 block; 3136 = 98*32
#define NHB  98
#define K3WB 64        // hw columns per k3 block; 3136 = 49*64
#define K3NB 49

// workspace layout (float offsets)
#define OFF_S8  0                         // 8 batches * 8 slots * 16384 (atomics)
#define OFF_R   1048576                   // 8*128 (atomics)
#define OFF_S   1049600                   // 8*16384 reduced Gram
#define OFF_M   1180672
#define OFF_Q   1311744
#define OFF_AV  1442816
#define OFF_CV  1443840
#define OFF_YB  1444864                   // Y bf16: 8*128*3136 ushort (1,605,632 fl)
#define ZEROFL  1049600                   // floats to zero (S8 + R)

typedef __attribute__((ext_vector_type(8)))  short bf16x8;
typedef __attribute__((ext_vector_type(16))) float f32x16;

__device__ __forceinline__ uint32_t fbits(float f){ union{float f;uint32_t u;}v; v.f=f; return v.u; }
__device__ __forceinline__ float bitsf(uint32_t u){ union{uint32_t u;float f;}v; v.u=u; return v.f; }
__device__ __forceinline__ float bf2f(unsigned short u){ return bitsf(((uint32_t)u)<<16); }
__device__ __forceinline__ unsigned short f2bf_rne(float f){
  uint32_t u = fbits(f);
  u += 0x7FFFu + ((u>>16)&1u);
  return (unsigned short)(u>>16);
}

#define MFMA32(a,b,c) __builtin_amdgcn_mfma_f32_32x32x16_bf16((a),(b),(c),0,0,0)

// ---------------- zk: zero the atomic accumulators (S8 + r), 4.2 MB --------
__global__ __launch_bounds__(256) void zk(float* __restrict__ w)
{
  const int i = (blockIdx.x*256 + threadIdx.x)*4;
  if(i < ZEROFL) *(float4*)(w + i) = make_float4(0.f,0.f,0.f,0.f);
}

// ---------------- k1: Gram via bf16 hi/lo MFMA + rowsum + Y(bf16) ----------
// R6 structure (best measured). Epilogue: S atomics into 8 spread slots,
// r atomics, Y written bf16 (halves Y traffic).
__global__ __launch_bounds__(256,3) void k1_gram(const float* __restrict__ x,
    float* __restrict__ S8, float* __restrict__ r, unsigned short* __restrict__ Yb)
{
  __shared__ __align__(16) short lds_h[2][4*129*8];   // 2 x 8.06 KB
  __shared__ __align__(16) short lds_l[2][4*129*8];
  const int b   = blockIdx.x / NHB;
  const int hb  = blockIdx.x % NHB;
  const int hw0 = hb * HWB;
  const int tid = threadIdx.x;
  const int lane = tid & 63, w = tid >> 6;
  const int wr = w >> 1, wc = w & 1;                  // 2x2 wave tiling
  const int cr = tid >> 3;                            // channel row (0..31)
  const int p  = tid & 7;                             // 16-B piece
  const int kc = p >> 1, hf = p & 1;
  const float* xb = x + (size_t)b*CCH*LLT + (size_t)cr*LLT + hw0 + 4*p;

  f32x16 acc[2][2];
  #pragma unroll
  for(int ai=0;ai<2;ai++)
    #pragma unroll
    for(int bi=0;bi<2;bi++)
      #pragma unroll
      for(int e=0;e<16;e++) acc[ai][bi][e] = 0.f;
  float yac[16];
  #pragma unroll
  for(int i=0;i<16;i++) yac[i]=0.f;

  float4 v[4];
  #pragma unroll
  for(int j=0;j<4;j++) v[j] = *(const float4*)(xb + (size_t)(32*j)*LLT);   // plane 0

#define SPLIT(bufi)                                                         \
  {                                                                         \
    _Pragma("unroll")                                                       \
    for(int j=0;j<4;j++){                                                   \
      const int c = 32*j + cr;                                              \
      const float x0=v[j].x, x1=v[j].y, x2=v[j].z, x3=v[j].w;               \
      const uint32_t a0=fbits(x0),a1=fbits(x1),a2=fbits(x2),a3=fbits(x3);   \
      const int h0 = __builtin_amdgcn_perm(a1, a0, 0x07060302u);            \
      const int h1 = __builtin_amdgcn_perm(a3, a2, 0x07060302u);            \
      const float l0 = x0 - bitsf(a0&0xFFFF0000u);                          \
      const float l1 = x1 - bitsf(a1&0xFFFF0000u);                          \
      const float l2 = x2 - bitsf(a2&0xFFFF0000u);                          \
      const float l3 = x3 - bitsf(a3&0xFFFF0000u);                          \
      const int g0 = __builtin_amdgcn_perm(fbits(l1), fbits(l0), 0x07060302u); \
      const int g1 = __builtin_amdgcn_perm(fbits(l3), fbits(l2), 0x07060302u); \
      const int sa = (kc*129 + c)*8 + 4*hf;                                 \
      *(int2*)&lds_h[bufi][sa] = make_int2(h0,h1);                          \
      *(int2*)&lds_l[bufi][sa] = make_int2(g0,g1);                          \
      yac[4*j+0]+=x0; yac[4*j+1]+=x1; yac[4*j+2]+=x2; yac[4*j+3]+=x3;       \
    }                                                                       \
  }

  SPLIT(0);
  __syncthreads();
  #pragma unroll
  for(int j=0;j<4;j++) v[j] = *(const float4*)(xb + (size_t)(32*j)*LLT + HWD);  // plane 1

  for(int n=0;n<NND;n++){
    const int cur = n & 1;
    #pragma unroll
    for(int ks=0;ks<2;ks++){
      const int kk = 2*ks + (lane>>5);
      const int rbase = (kk*129 + (lane&31))*8;
      const bf16x8 a0h = *(const bf16x8*)&lds_h[cur][rbase + (64*wr    )*8];
      const bf16x8 a0l = *(const bf16x8*)&lds_l[cur][rbase + (64*wr    )*8];
      const bf16x8 a1h = *(const bf16x8*)&lds_h[cur][rbase + (64*wr+32)*8];
      const bf16x8 a1l = *(const bf16x8*)&lds_l[cur][rbase + (64*wr+32)*8];
      const bf16x8 b0h = *(const bf16x8*)&lds_h[cur][rbase + (64*wc    )*8];
      const bf16x8 b0l = *(const bf16x8*)&lds_l[cur][rbase + (64*wc    )*8];
      const bf16x8 b1h = *(const bf16x8*)&lds_h[cur][rbase + (64*wc+32)*8];
      const bf16x8 b1l = *(const bf16x8*)&lds_l[cur][rbase + (64*wc+32)*8];
      acc[0][0] = MFMA32(a0h, b0h, acc[0][0]);
      acc[0][0] = MFMA32(a0h, b0l, acc[0][0]);
      acc[0][0] = MFMA32(a0l, b0h, acc[0][0]);
      acc[0][1] = MFMA32(a0h, b1h, acc[0][1]);
      acc[0][1] = MFMA32(a0h, b1l, acc[0][1]);
      acc[0][1] = MFMA32(a0l, b1h, acc[0][1]);
      acc[1][0] = MFMA32(a1h, b0h, acc[1][0]);
      acc[1][0] = MFMA32(a1h, b0l, acc[1][0]);
      acc[1][0] = MFMA32(a1l, b0h, acc[1][0]);
      acc[1][1] = MFMA32(a1h, b1h, acc[1][1]);
      acc[1][1] = MFMA32(a1h, b1l, acc[1][1]);
      acc[1][1] = MFMA32(a1l, b1h, acc[1][1]);
    }
    if(n+1 < NND){
      SPLIT(cur^1);
      __syncthreads();
      if(n+2 < NND){
        #pragma unroll
        for(int j=0;j<4;j++)
          v[j] = *(const float4*)(xb + (size_t)(32*j)*LLT + (size_t)(n+2)*HWD);
      }
    }
  }
#undef SPLIT

  // ---- epilogue: Y (bf16), r (atomic), S (atomic into slot blockIdx&7) ----
  #pragma unroll
  for(int j=0;j<4;j++){
    ushort4 o4;
    o4.x = f2bf_rne(yac[4*j+0]*0.0625f);
    o4.y = f2bf_rne(yac[4*j+1]*0.0625f);
    o4.z = f2bf_rne(yac[4*j+2]*0.0625f);
    o4.w = f2bf_rne(yac[4*j+3]*0.0625f);
    *(ushort4*)(Yb + ((size_t)b*CCH + 32*j + cr)*HWD + hw0 + 4*p) = o4;
  }
  #pragma unroll
  for(int j=0;j<4;j++){
    float s = yac[4*j]+yac[4*j+1]+yac[4*j+2]+yac[4*j+3];
    #pragma unroll
    for(int st=1;st<8;st<<=1) s += __shfl_xor(s, st, 8);
    if(p==0) atomicAdd(&r[b*CCH + 32*j + cr], s);
  }

  float* Sb = S8 + (size_t)(b*8 + (blockIdx.x & 7))*CCH*CCH;
  const int col = lane & 31, roff = 4*(lane>>5);
  #pragma unroll
  for(int ai=0;ai<2;ai++)
    #pragma unroll
    for(int bi=0;bi<2;bi++)
      #pragma unroll
      for(int reg=0;reg<16;reg++){
        const int row = 64*wr + 32*ai + roff + (reg&3) + 8*(reg>>2);
        atomicAdd(&Sb[(size_t)row*CCH + 64*wc + 32*bi + col], acc[ai][bi][reg]);
      }
}

// ---------------- k1r8: S[b] = sum_slot S8[b][slot]  (4 MB read) ------------
__global__ __launch_bounds__(256) void k1r8(const float* __restrict__ S8,
                                            float* __restrict__ S)
{
  const int b = blockIdx.x >> 4;
  const int i = (blockIdx.x & 15)*1024 + threadIdx.x*4;
  const float* p = S8 + (size_t)b*8*CCH*CCH + i;
  float4 s = make_float4(0.f,0.f,0.f,0.f);
  #pragma unroll
  for(int sl=0;sl<8;sl++){
    float4 v = *(const float4*)(p + (size_t)sl*CCH*CCH);
    s.x+=v.x; s.y+=v.y; s.z+=v.z; s.w+=v.w;
  }
  *(float4*)(S + (size_t)b*CCH*CCH + i) = s;
}

// ------- k2ab: G = WqSWk^T + bias, softmax -> A (LDS), M = A@Wv, av = A@bv --
__global__ __launch_bounds__(256) void k2ab(const float* __restrict__ S, const float* __restrict__ r,
    const float* __restrict__ wq, const float* __restrict__ bq,
    const float* __restrict__ wk, const float* __restrict__ bk,
    const float* __restrict__ wv, const float* __restrict__ bv,
    float* __restrict__ M, float* __restrict__ av)
{
  __shared__ __align__(16) float t1[16][132];
  __shared__ float rb_s[CCH];
  __shared__ float wrk_s[CCH];
  __shared__ float wrq_s[16];
  const int b   = blockIdx.x >> 3;
  const int r0  = (blockIdx.x & 7) * 16;
  const int tid = threadIdx.x;
  const float* Sb = S + (size_t)b*CCH*CCH;

  if(tid < CCH) rb_s[tid] = r[b*CCH + tid];
  __syncthreads();

  if(tid < CCH){
    float s = 0.f;
    for(int m=0;m<CCH;m++) s += wk[(size_t)tid*CCH+m]*rb_s[m];
    wrk_s[tid] = s;
  } else if(tid < CCH+16){
    const int rr2 = tid - CCH;
    float s = 0.f;
    for(int m=0;m<CCH;m++) s += wq[(size_t)(r0+rr2)*CCH+m]*rb_s[m];
    wrq_s[rr2] = s;
  }

  const int rr = tid >> 4;
  const int c0 = (tid & 15) * 8;
  { // T1 = W_q[rows] @ S
    float a8[8] = {0,0,0,0,0,0,0,0};
    const float* wqr = wq + (size_t)(r0+rr)*CCH;
    for(int m4=0;m4<32;m4++){
      float4 w4 = *(const float4*)(wqr + 4*m4);
      const float wl[4] = {w4.x,w4.y,w4.z,w4.w};
      #pragma unroll
      for(int mm=0;mm<4;mm++){
        const int m = 4*m4+mm;
        const float w = wl[mm];
        float4 s0 = *(const float4*)(Sb + (size_t)m*CCH + c0);
        float4 s1 = *(const float4*)(Sb + (size_t)m*CCH + c0 + 4);
        a8[0]=fmaf(w,s0.x,a8[0]); a8[1]=fmaf(w,s0.y,a8[1]);
        a8[2]=fmaf(w,s0.z,a8[2]); a8[3]=fmaf(w,s0.w,a8[3]);
        a8[4]=fmaf(w,s1.x,a8[4]); a8[5]=fmaf(w,s1.y,a8[5]);
        a8[6]=fmaf(w,s1.z,a8[6]); a8[7]=fmaf(w,s1.w,a8[7]);
      }
    }
    #pragma unroll
    for(int j=0;j<8;j++) t1[rr][c0+j] = a8[j];
  }
  __syncthreads();

  const int j0 = c0;
  float g[8] = {0,0,0,0,0,0,0,0};
  for(int c4=0;c4<32;c4++){
    float4 tv = *(const float4*)(&t1[rr][4*c4]);
    #pragma unroll
    for(int jj=0;jj<8;jj++){
      float4 w4 = *(const float4*)(wk + (size_t)(j0+jj)*CCH + 4*c4);
      g[jj]=fmaf(tv.x,w4.x,g[jj]); g[jj]=fmaf(tv.y,w4.y,g[jj]);
      g[jj]=fmaf(tv.z,w4.z,g[jj]); g[jj]=fmaf(tv.w,w4.w,g[jj]);
    }
  }
  const float bqr  = bq[r0+rr];
  const float wrqr = wrq_s[rr];
  #pragma unroll
  for(int jj=0;jj<8;jj++)
    g[jj] += wrqr*bk[j0+jj] + bqr*wrk_s[j0+jj] + (float)LLT*bqr*bk[j0+jj];

  float mx = g[0];
  #pragma unroll
  for(int jj=1;jj<8;jj++) mx = fmaxf(mx, g[jj]);
  #pragma unroll
  for(int s=1;s<16;s<<=1) mx = fmaxf(mx, __shfl_xor(mx, s, 16));
  float ex[8], sum=0.f;
  #pragma unroll
  for(int jj=0;jj<8;jj++){ ex[jj] = expf(g[jj]-mx); sum += ex[jj]; }
  #pragma unroll
  for(int s=1;s<16;s<<=1) sum += __shfl_xor(sum, s, 16);
  const float inv = 1.0f/sum;

  float pa = 0.f;
  #pragma unroll
  for(int jj=0;jj<8;jj++) pa += ex[jj]*inv*bv[j0+jj];
  #pragma unroll
  for(int s=1;s<16;s<<=1) pa += __shfl_xor(pa, s, 16);
  if((tid&15)==0) av[b*CCH + r0+rr] = pa;

  __syncthreads();
  #pragma unroll
  for(int jj=0;jj<8;jj++) t1[rr][j0+jj] = ex[jj]*inv;
  __syncthreads();

  { // M = A @ Wv
    float a8[8] = {0,0,0,0,0,0,0,0};
    for(int k4=0;k4<32;k4++){
      float4 a4 = *(const float4*)(&t1[rr][4*k4]);
      const float al[4] = {a4.x,a4.y,a4.z,a4.w};
      #pragma unroll
      for(int kk=0;kk<4;kk++){
        const int k = 4*k4+kk;
        const float wgt = al[kk];
        float4 v0 = *(const float4*)(wv + (size_t)k*CCH + c0);
        float4 v1 = *(const float4*)(wv + (size_t)k*CCH + c0 + 4);
        a8[0]=fmaf(wgt,v0.x,a8[0]); a8[1]=fmaf(wgt,v0.y,a8[1]);
        a8[2]=fmaf(wgt,v0.z,a8[2]); a8[3]=fmaf(wgt,v0.w,a8[3]);
        a8[4]=fmaf(wgt,v1.x,a8[4]); a8[5]=fmaf(wgt,v1.y,a8[5]);
        a8[6]=fmaf(wgt,v1.z,a8[6]); a8[7]=fmaf(wgt,v1.w,a8[7]);
      }
    }
    float* Mr = M + ((size_t)b*CCH + r0+rr)*CCH + c0;
    *(float4*)(Mr  ) = make_float4(a8[0],a8[1],a8[2],a8[3]);
    *(float4*)(Mr+4) = make_float4(a8[4],a8[5],a8[6],a8[7]);
  }
}

// ---------------- k2c: Q = W_o @ M + I ;  c = W_o av + b_o ------------------
__global__ __launch_bounds__(256) void k2c(const float* __restrict__ M,
    const float* __restrict__ wo, const float* __restrict__ bo,
    const float* __restrict__ av, float* __restrict__ Q, float* __restrict__ cv)
{
  const int b  = blockIdx.x >> 3;
  const int o0 = (blockIdx.x & 7)*16;
  const int tid = threadIdx.x;
  const int rr = tid>>4, c0 = (tid&15)*8;
  const int o  = o0 + rr;
  const float* wor = wo + (size_t)o*CCH;
  const float* Mb  = M + (size_t)b*CCH*CCH;
  float a8[8] = {0,0,0,0,0,0,0,0};
  for(int m4=0;m4<32;m4++){
    float4 w4 = *(const float4*)(wor + 4*m4);
    const float wl[4] = {w4.x,w4.y,w4.z,w4.w};
    #pragma unroll
    for(int mm=0;mm<4;mm++){
      const int m = 4*m4+mm;
      const float w = wl[mm];
      float4 v0 = *(const float4*)(Mb + (size_t)m*CCH + c0);
      float4 v1 = *(const float4*)(Mb + (size_t)m*CCH + c0 + 4);
      a8[0]=fmaf(w,v0.x,a8[0]); a8[1]=fmaf(w,v0.y,a8[1]);
      a8[2]=fmaf(w,v0.z,a8[2]); a8[3]=fmaf(w,v0.w,a8[3]);
      a8[4]=fmaf(w,v1.x,a8[4]); a8[5]=fmaf(w,v1.y,a8[5]);
      a8[6]=fmaf(w,v1.z,a8[6]); a8[7]=fmaf(w,v1.w,a8[7]);
    }
  }
  #pragma unroll
  for(int j=0;j<8;j++) if(o == c0+j) a8[j] += 1.0f;   // +I (residual folded)
  float* Qr = Q + ((size_t)b*CCH + o)*CCH + c0;
  *(float4*)(Qr  ) = make_float4(a8[0],a8[1],a8[2],a8[3]);
  *(float4*)(Qr+4) = make_float4(a8[4],a8[5],a8[6],a8[7]);

  if(tid < 16){
    const int oo = o0 + tid;
    float s = 0.f;
    for(int m=0;m<CCH;m++) s += wo[(size_t)oo*CCH+m]*av[b*CCH+m];
    cv[b*CCH + oo] = s + bo[oo];
  }
}

// ---------------- k3: out = Q @ Y(bf16) + c ---------------------------------
__global__ __launch_bounds__(256,2) void k3(const float* __restrict__ Q,
    const float* __restrict__ cv, const unsigned short* __restrict__ Ybf,
    float* __restrict__ out)
{
  __shared__ __align__(16) float4 qs[4096];             // 64 KB
  const int b   = blockIdx.x / K3NB;
  const int hb  = blockIdx.x % K3NB;
  const int hw0 = hb * K3WB;
  const int tid = threadIdx.x;

  const float4* Qg = (const float4*)(Q + (size_t)b*CCH*CCH);
  #pragma unroll
  for(int it=0; it<16; it++){
    const int idx = it*256 + tid;
    const int row = idx >> 5, ch = idx & 31;
    qs[(row<<5) | (ch ^ (row>>3))] = Qg[idx];
  }
  __syncthreads();

  const int tx = tid & 15, ty = tid >> 4;
  const int o0 = tx*8;
  const int hg = ty*4;
  float acc[8][4];
  #pragma unroll
  for(int i=0;i<8;i++){ acc[i][0]=0.f; acc[i][1]=0.f; acc[i][2]=0.f; acc[i][3]=0.f; }

  const unsigned short* Ybb = Ybf + (size_t)b*CCH*HWD + hw0 + hg;
  for(int c4=0;c4<32;c4++){
    float4 yv[4];
    #pragma unroll
    for(int mm=0;mm<4;mm++){
      ushort4 u = *(const ushort4*)(Ybb + (size_t)(4*c4+mm)*HWD);
      yv[mm] = make_float4(bf2f(u.x), bf2f(u.y), bf2f(u.z), bf2f(u.w));
    }
    #pragma unroll
    for(int i=0;i<8;i++){
      const int row = o0 + i;
      const float4 q4 = qs[(row<<5) | (c4 ^ tx)];
      const float ql[4] = {q4.x,q4.y,q4.z,q4.w};
      #pragma unroll
      for(int mm=0;mm<4;mm++){
        acc[i][0]=fmaf(ql[mm],yv[mm].x,acc[i][0]);
        acc[i][1]=fmaf(ql[mm],yv[mm].y,acc[i][1]);
        acc[i][2]=fmaf(ql[mm],yv[mm].z,acc[i][2]);
        acc[i][3]=fmaf(ql[mm],yv[mm].w,acc[i][3]);
      }
    }
  }
  #pragma unroll
  for(int i=0;i<8;i++){
    const float c = cv[b*CCH + o0+i];
    float4 o4 = make_float4(acc[i][0]+c, acc[i][1]+c, acc[i][2]+c, acc[i][3]+c);
    *(float4*)(out + ((size_t)b*CCH + o0+i)*HWD + hw0 + hg) = o4;
  }
}

extern "C" void kernel_launch(void* const* d_in, const int* in_sizes, int n_in,
                              void* d_out, int out_size, void* d_ws, size_t ws_size,
                              hipStream_t stream) {
  const float* x  = (const float*)d_in[0];
  const float* wq = (const float*)d_in[1];
  const float* bq = (const float*)d_in[2];
  const float* wk = (const float*)d_in[3];
  const float* bk = (const float*)d_in[4];
  const float* wv = (const float*)d_in[5];
  const float* bv = (const float*)d_in[6];
  const float* wo = (const float*)d_in[7];
  const float* bo = (const float*)d_in[8];
  float* out = (float*)d_out;
  float* ws  = (float*)d_ws;
  unsigned short* ybf = (unsigned short*)(ws + OFF_YB);

  zk     <<<1025, 256, 0, stream>>>(ws + OFF_S8);
  k1_gram<<<BB*NHB, 256, 0, stream>>>(x, ws+OFF_S8, ws+OFF_R, ybf);
  k1r8   <<<128, 256, 0, stream>>>(ws+OFF_S8, ws+OFF_S);
  k2ab   <<<64, 256, 0, stream>>>(ws+OFF_S, ws+OFF_R, wq, bq, wk, bk, wv, bv,
                                  ws+OFF_M, ws+OFF_AV);
  k2c    <<<64, 256, 0, stream>>>(ws+OFF_M, wo, bo, ws+OFF_AV, ws+OFF_Q, ws+OFF_CV);
  k3     <<<BB*K3NB, 256, 0, stream>>>(ws+OFF_Q, ws+OFF_CV, ybf, out);
}

// Round 11
// 175.299 us; speedup vs baseline: 1.4896x; 1.0701x over previous
//
#include <hip/hip_runtime.h>
#include <hip/hip_bf16.h>
#include <cstdint>

#define BB   8
#define CCH  128
#define NND  16
#define HWD  3136      // 56*56
#define LLT  50176     // 16*3136 = 49*1024
#define NWIN 49        // l-windows of 1024 per batch (kA)
#define K3WB 64        // hw columns per k3 block; 3136 = 49*64
#define K3NB 49

// workspace layout (float offsets) — no zero-init required anywhere
#define OFF_SP  0                         // 8*49*16384 Gram partials (plain stores)
#define OFF_S   6422528                   // 8*16384 reduced Gram
#define OFF_R   6553600                   // 8*128 rowsums (exclusive writes)
#define OFF_M   6554624
#define OFF_Q   6685696
#define OFF_AV  6816768
#define OFF_CV  6817792
#define OFF_YB  6818816                   // Y bf16: 8*128*3136 ushorts

typedef __attribute__((ext_vector_type(8)))  short bf16x8;
typedef __attribute__((ext_vector_type(16))) float f32x16;

__device__ __forceinline__ uint32_t fbits(float f){ union{float f;uint32_t u;}v; v.f=f; return v.u; }
__device__ __forceinline__ float bitsf(uint32_t u){ union{uint32_t u;float f;}v; v.u=u; return v.f; }
__device__ __forceinline__ float bf2f(unsigned short u){ return bitsf(((uint32_t)u)<<16); }
__device__ __forceinline__ unsigned short f2bf_rne(float f){
  uint32_t u = fbits(f);
  u += 0x7FFFu + ((u>>16)&1u);
  return (unsigned short)(u>>16);
}

#define MFMA32(a,b,c) __builtin_amdgcn_mfma_f32_32x32x16_bf16((a),(b),(c),0,0,0)

// ---------------- kA: Gram over flat-l windows (contiguous reads) -----------
// block = (b, window of 1024 l). 16 stages of K=64. Per load-instr a wave
// covers 4 channels x 256 B CONTIGUOUS (no 200-KB stride pattern).
__global__ __launch_bounds__(256,2) void kA(const float* __restrict__ x,
                                            float* __restrict__ Sp)
{
  __shared__ __align__(16) short lds_h[8*129*8];   // 16.5 KB
  __shared__ __align__(16) short lds_l[8*129*8];   // 16.5 KB
  const int b  = blockIdx.x / NWIN;
  const int l0 = (blockIdx.x % NWIN) * 1024;
  const int tid = threadIdx.x;
  const int lane = tid & 63, w = tid >> 6;
  const int wr = w >> 1, wc = w & 1;               // 2x2 wave tiling
  const int q  = lane & 15;                        // position within 64-float run
  const int csub = lane >> 4;                      // 0..3
  const int chunk = q >> 1, pos4 = q & 1;          // LDS frag slot
  const float* xb = x + (size_t)b*CCH*LLT + l0 + 4*q;

  f32x16 acc[2][2];
  #pragma unroll
  for(int ai=0;ai<2;ai++)
    #pragma unroll
    for(int bi=0;bi<2;bi++)
      #pragma unroll
      for(int e=0;e<16;e++) acc[ai][bi][e] = 0.f;

  float4 v[8];

#define LOADS(ss)                                                           \
  { _Pragma("unroll")                                                       \
    for(int i=0;i<8;i++){                                                   \
      const int c = 32*w + 4*i + csub;                                      \
      v[i] = *(const float4*)(xb + (size_t)c*LLT + (ss)*64);                \
    } }

#define SPLITW()                                                            \
  { _Pragma("unroll")                                                       \
    for(int i=0;i<8;i++){                                                   \
      const int c = 32*w + 4*i + csub;                                      \
      const float x0=v[i].x, x1=v[i].y, x2=v[i].z, x3=v[i].w;               \
      const uint32_t a0=fbits(x0),a1=fbits(x1),a2=fbits(x2),a3=fbits(x3);   \
      const int h0 = __builtin_amdgcn_perm(a1, a0, 0x07060302u);            \
      const int h1 = __builtin_amdgcn_perm(a3, a2, 0x07060302u);            \
      const float l0_ = x0 - bitsf(a0&0xFFFF0000u);                         \
      const float l1_ = x1 - bitsf(a1&0xFFFF0000u);                         \
      const float l2_ = x2 - bitsf(a2&0xFFFF0000u);                         \
      const float l3_ = x3 - bitsf(a3&0xFFFF0000u);                         \
      const int g0 = __builtin_amdgcn_perm(fbits(l1_), fbits(l0_), 0x07060302u); \
      const int g1 = __builtin_amdgcn_perm(fbits(l3_), fbits(l2_), 0x07060302u); \
      const int sa = ((chunk*129 + c)*8 + 4*pos4);                          \
      *(int2*)&lds_h[sa] = make_int2(h0,h1);                                \
      *(int2*)&lds_l[sa] = make_int2(g0,g1);                                \
    } }

  LOADS(0);
  for(int s=0;s<16;s++){
    SPLITW();                    // stage s into LDS
    __syncthreads();
    if(s<15) LOADS(s+1);         // next stage in flight during compute
    #pragma unroll
    for(int ks=0;ks<4;ks++){
      const int kk = 2*ks + (lane>>5);
      const int rbase = (kk*129 + (lane&31))*8;
      const bf16x8 a0h = *(const bf16x8*)&lds_h[rbase + (64*wr    )*8];
      const bf16x8 a0l = *(const bf16x8*)&lds_l[rbase + (64*wr    )*8];
      const bf16x8 a1h = *(const bf16x8*)&lds_h[rbase + (64*wr+32)*8];
      const bf16x8 a1l = *(const bf16x8*)&lds_l[rbase + (64*wr+32)*8];
      const bf16x8 b0h = *(const bf16x8*)&lds_h[rbase + (64*wc    )*8];
      const bf16x8 b0l = *(const bf16x8*)&lds_l[rbase + (64*wc    )*8];
      const bf16x8 b1h = *(const bf16x8*)&lds_h[rbase + (64*wc+32)*8];
      const bf16x8 b1l = *(const bf16x8*)&lds_l[rbase + (64*wc+32)*8];
      acc[0][0] = MFMA32(a0h, b0h, acc[0][0]);
      acc[0][0] = MFMA32(a0h, b0l, acc[0][0]);
      acc[0][0] = MFMA32(a0l, b0h, acc[0][0]);
      acc[0][1] = MFMA32(a0h, b1h, acc[0][1]);
      acc[0][1] = MFMA32(a0h, b1l, acc[0][1]);
      acc[0][1] = MFMA32(a0l, b1h, acc[0][1]);
      acc[1][0] = MFMA32(a1h, b0h, acc[1][0]);
      acc[1][0] = MFMA32(a1h, b0l, acc[1][0]);
      acc[1][0] = MFMA32(a1l, b0h, acc[1][0]);
      acc[1][1] = MFMA32(a1h, b1h, acc[1][1]);
      acc[1][1] = MFMA32(a1h, b1l, acc[1][1]);
      acc[1][1] = MFMA32(a1l, b1h, acc[1][1]);
    }
    __syncthreads();
  }
#undef LOADS
#undef SPLITW

  // Sp partial, plain exclusive stores
  float* Sb = Sp + (size_t)blockIdx.x*CCH*CCH;
  const int col = lane & 31, roff = 4*(lane>>5);
  #pragma unroll
  for(int ai=0;ai<2;ai++)
    #pragma unroll
    for(int bi=0;bi<2;bi++)
      #pragma unroll
      for(int reg=0;reg<16;reg++){
        const int row = 64*wr + 32*ai + roff + (reg&3) + 8*(reg>>2);
        Sb[(size_t)row*CCH + 64*wc + 32*bi + col] = acc[ai][bi][reg];
      }
}

// ---------------- kY: Y = mean_n x (bf16) + exact fp32 rowsum ---------------
// block = (b,c). Reads channel's 200 KB fully sequentially (1 KB/instr).
__global__ __launch_bounds__(256) void kY(const float* __restrict__ x,
    unsigned short* __restrict__ Yb, float* __restrict__ r)
{
  __shared__ float red[256];
  const int bc = blockIdx.x;            // b*128 + c
  const int t  = threadIdx.x;
  const float* xc = x + (size_t)bc*LLT;

  float4 y0 = make_float4(0,0,0,0), y1 = y0, y2 = y0, y3 = y0;
  for(int n=0;n<NND;n++){
    const float* xp = xc + n*HWD;
    float4 v0 = *(const float4*)(xp + 4*t);
    float4 v1 = *(const float4*)(xp + 4*(t+256));
    float4 v2 = *(const float4*)(xp + 4*(t+512));
    y0.x+=v0.x; y0.y+=v0.y; y0.z+=v0.z; y0.w+=v0.w;
    y1.x+=v1.x; y1.y+=v1.y; y1.z+=v1.z; y1.w+=v1.w;
    y2.x+=v2.x; y2.y+=v2.y; y2.z+=v2.z; y2.w+=v2.w;
    if(t<16){
      float4 v3 = *(const float4*)(xp + 4*(t+768));
      y3.x+=v3.x; y3.y+=v3.y; y3.z+=v3.z; y3.w+=v3.w;
    }
  }
  unsigned short* Yc = Yb + (size_t)bc*HWD;
  ushort4 o;
  o.x=f2bf_rne(y0.x*0.0625f); o.y=f2bf_rne(y0.y*0.0625f);
  o.z=f2bf_rne(y0.z*0.0625f); o.w=f2bf_rne(y0.w*0.0625f);
  *(ushort4*)(Yc + 4*t) = o;
  o.x=f2bf_rne(y1.x*0.0625f); o.y=f2bf_rne(y1.y*0.0625f);
  o.z=f2bf_rne(y1.z*0.0625f); o.w=f2bf_rne(y1.w*0.0625f);
  *(ushort4*)(Yc + 4*(t+256)) = o;
  o.x=f2bf_rne(y2.x*0.0625f); o.y=f2bf_rne(y2.y*0.0625f);
  o.z=f2bf_rne(y2.z*0.0625f); o.w=f2bf_rne(y2.w*0.0625f);
  *(ushort4*)(Yc + 4*(t+512)) = o;
  if(t<16){
    o.x=f2bf_rne(y3.x*0.0625f); o.y=f2bf_rne(y3.y*0.0625f);
    o.z=f2bf_rne(y3.z*0.0625f); o.w=f2bf_rne(y3.w*0.0625f);
    *(ushort4*)(Yc + 4*(t+768)) = o;
  }
  float s = y0.x+y0.y+y0.z+y0.w + y1.x+y1.y+y1.z+y1.w + y2.x+y2.y+y2.z+y2.w;
  if(t<16) s += y3.x+y3.y+y3.z+y3.w;
  red[t] = s;
  __syncthreads();
  #pragma unroll
  for(int off=128; off; off>>=1){
    if(t<off) red[t] += red[t+off];
    __syncthreads();
  }
  if(t==0) r[bc] = red[0];
}

// ---------------- k1r: S[b] = sum_w Sp[b,w] ---------------------------------
__global__ __launch_bounds__(256) void k1r(const float* __restrict__ Sp,
                                           float* __restrict__ S)
{
  const int b = blockIdx.x >> 4;
  const int i = (blockIdx.x & 15)*1024 + threadIdx.x*4;
  const float* p = Sp + (size_t)b*NWIN*CCH*CCH + i;
  float4 s = make_float4(0.f,0.f,0.f,0.f);
  for(int wdw=0; wdw<NWIN; wdw++){
    float4 v = *(const float4*)(p + (size_t)wdw*CCH*CCH);
    s.x+=v.x; s.y+=v.y; s.z+=v.z; s.w+=v.w;
  }
  *(float4*)(S + (size_t)b*CCH*CCH + i) = s;
}

// ------- k2ab: G = WqSWk^T + bias, softmax -> A (LDS), M = A@Wv, av = A@bv --
__global__ __launch_bounds__(256) void k2ab(const float* __restrict__ S, const float* __restrict__ r,
    const float* __restrict__ wq, const float* __restrict__ bq,
    const float* __restrict__ wk, const float* __restrict__ bk,
    const float* __restrict__ wv, const float* __restrict__ bv,
    float* __restrict__ M, float* __restrict__ av)
{
  __shared__ __align__(16) float t1[16][132];
  __shared__ float rb_s[CCH];
  __shared__ float wrk_s[CCH];
  __shared__ float wrq_s[16];
  const int b   = blockIdx.x >> 3;
  const int r0  = (blockIdx.x & 7) * 16;
  const int tid = threadIdx.x;
  const float* Sb = S + (size_t)b*CCH*CCH;

  if(tid < CCH) rb_s[tid] = r[b*CCH + tid];
  __syncthreads();

  if(tid < CCH){
    float s = 0.f;
    for(int m=0;m<CCH;m++) s += wk[(size_t)tid*CCH+m]*rb_s[m];
    wrk_s[tid] = s;
  } else if(tid < CCH+16){
    const int rr2 = tid - CCH;
    float s = 0.f;
    for(int m=0;m<CCH;m++) s += wq[(size_t)(r0+rr2)*CCH+m]*rb_s[m];
    wrq_s[rr2] = s;
  }

  const int rr = tid >> 4;
  const int c0 = (tid & 15) * 8;
  { // T1 = W_q[rows] @ S
    float a8[8] = {0,0,0,0,0,0,0,0};
    const float* wqr = wq + (size_t)(r0+rr)*CCH;
    for(int m4=0;m4<32;m4++){
      float4 w4 = *(const float4*)(wqr + 4*m4);
      const float wl[4] = {w4.x,w4.y,w4.z,w4.w};
      #pragma unroll
      for(int mm=0;mm<4;mm++){
        const int m = 4*m4+mm;
        const float w = wl[mm];
        float4 s0 = *(const float4*)(Sb + (size_t)m*CCH + c0);
        float4 s1 = *(const float4*)(Sb + (size_t)m*CCH + c0 + 4);
        a8[0]=fmaf(w,s0.x,a8[0]); a8[1]=fmaf(w,s0.y,a8[1]);
        a8[2]=fmaf(w,s0.z,a8[2]); a8[3]=fmaf(w,s0.w,a8[3]);
        a8[4]=fmaf(w,s1.x,a8[4]); a8[5]=fmaf(w,s1.y,a8[5]);
        a8[6]=fmaf(w,s1.z,a8[6]); a8[7]=fmaf(w,s1.w,a8[7]);
      }
    }
    #pragma unroll
    for(int j=0;j<8;j++) t1[rr][c0+j] = a8[j];
  }
  __syncthreads();

  const int j0 = c0;
  float g[8] = {0,0,0,0,0,0,0,0};
  for(int c4=0;c4<32;c4++){
    float4 tv = *(const float4*)(&t1[rr][4*c4]);
    #pragma unroll
    for(int jj=0;jj<8;jj++){
      float4 w4 = *(const float4*)(wk + (size_t)(j0+jj)*CCH + 4*c4);
      g[jj]=fmaf(tv.x,w4.x,g[jj]); g[jj]=fmaf(tv.y,w4.y,g[jj]);
      g[jj]=fmaf(tv.z,w4.z,g[jj]); g[jj]=fmaf(tv.w,w4.w,g[jj]);
    }
  }
  const float bqr  = bq[r0+rr];
  const float wrqr = wrq_s[rr];
  #pragma unroll
  for(int jj=0;jj<8;jj++)
    g[jj] += wrqr*bk[j0+jj] + bqr*wrk_s[j0+jj] + (float)LLT*bqr*bk[j0+jj];

  float mx = g[0];
  #pragma unroll
  for(int jj=1;jj<8;jj++) mx = fmaxf(mx, g[jj]);
  #pragma unroll
  for(int s=1;s<16;s<<=1) mx = fmaxf(mx, __shfl_xor(mx, s, 16));
  float ex[8], sum=0.f;
  #pragma unroll
  for(int jj=0;jj<8;jj++){ ex[jj] = expf(g[jj]-mx); sum += ex[jj]; }
  #pragma unroll
  for(int s=1;s<16;s<<=1) sum += __shfl_xor(sum, s, 16);
  const float inv = 1.0f/sum;

  float pa = 0.f;
  #pragma unroll
  for(int jj=0;jj<8;jj++) pa += ex[jj]*inv*bv[j0+jj];
  #pragma unroll
  for(int s=1;s<16;s<<=1) pa += __shfl_xor(pa, s, 16);
  if((tid&15)==0) av[b*CCH + r0+rr] = pa;

  __syncthreads();
  #pragma unroll
  for(int jj=0;jj<8;jj++) t1[rr][j0+jj] = ex[jj]*inv;
  __syncthreads();

  { // M = A @ Wv
    float a8[8] = {0,0,0,0,0,0,0,0};
    for(int k4=0;k4<32;k4++){
      float4 a4 = *(const float4*)(&t1[rr][4*k4]);
      const float al[4] = {a4.x,a4.y,a4.z,a4.w};
      #pragma unroll
      for(int kk=0;kk<4;kk++){
        const int k = 4*k4+kk;
        const float wgt = al[kk];
        float4 v0 = *(const float4*)(wv + (size_t)k*CCH + c0);
        float4 v1 = *(const float4*)(wv + (size_t)k*CCH + c0 + 4);
        a8[0]=fmaf(wgt,v0.x,a8[0]); a8[1]=fmaf(wgt,v0.y,a8[1]);
        a8[2]=fmaf(wgt,v0.z,a8[2]); a8[3]=fmaf(wgt,v0.w,a8[3]);
        a8[4]=fmaf(wgt,v1.x,a8[4]); a8[5]=fmaf(wgt,v1.y,a8[5]);
        a8[6]=fmaf(wgt,v1.z,a8[6]); a8[7]=fmaf(wgt,v1.w,a8[7]);
      }
    }
    float* Mr = M + ((size_t)b*CCH + r0+rr)*CCH + c0;
    *(float4*)(Mr  ) = make_float4(a8[0],a8[1],a8[2],a8[3]);
    *(float4*)(Mr+4) = make_float4(a8[4],a8[5],a8[6],a8[7]);
  }
}

// ---------------- k2c: Q = W_o @ M + I ;  c = W_o av + b_o ------------------
__global__ __launch_bounds__(256) void k2c(const float* __restrict__ M,
    const float* __restrict__ wo, const float* __restrict__ bo,
    const float* __restrict__ av, float* __restrict__ Q, float* __restrict__ cv)
{
  const int b  = blockIdx.x >> 3;
  const int o0 = (blockIdx.x & 7)*16;
  const int tid = threadIdx.x;
  const int rr = tid>>4, c0 = (tid&15)*8;
  const int o  = o0 + rr;
  const float* wor = wo + (size_t)o*CCH;
  const float* Mb  = M + (size_t)b*CCH*CCH;
  float a8[8] = {0,0,0,0,0,0,0,0};
  for(int m4=0;m4<32;m4++){
    float4 w4 = *(const float4*)(wor + 4*m4);
    const float wl[4] = {w4.x,w4.y,w4.z,w4.w};
    #pragma unroll
    for(int mm=0;mm<4;mm++){
      const int m = 4*m4+mm;
      const float w = wl[mm];
      float4 v0 = *(const float4*)(Mb + (size_t)m*CCH + c0);
      float4 v1 = *(const float4*)(Mb + (size_t)m*CCH + c0 + 4);
      a8[0]=fmaf(w,v0.x,a8[0]); a8[1]=fmaf(w,v0.y,a8[1]);
      a8[2]=fmaf(w,v0.z,a8[2]); a8[3]=fmaf(w,v0.w,a8[3]);
      a8[4]=fmaf(w,v1.x,a8[4]); a8[5]=fmaf(w,v1.y,a8[5]);
      a8[6]=fmaf(w,v1.z,a8[6]); a8[7]=fmaf(w,v1.w,a8[7]);
    }
  }
  #pragma unroll
  for(int j=0;j<8;j++) if(o == c0+j) a8[j] += 1.0f;   // +I (residual folded)
  float* Qr = Q + ((size_t)b*CCH + o)*CCH + c0;
  *(float4*)(Qr  ) = make_float4(a8[0],a8[1],a8[2],a8[3]);
  *(float4*)(Qr+4) = make_float4(a8[4],a8[5],a8[6],a8[7]);

  if(tid < 16){
    const int oo = o0 + tid;
    float s = 0.f;
    for(int m=0;m<CCH;m++) s += wo[(size_t)oo*CCH+m]*av[b*CCH+m];
    cv[b*CCH + oo] = s + bo[oo];
  }
}

// ---------------- k3: out = Q @ Y(bf16) + c ---------------------------------
__global__ __launch_bounds__(256,2) void k3(const float* __restrict__ Q,
    const float* __restrict__ cv, const unsigned short* __restrict__ Ybf,
    float* __restrict__ out)
{
  __shared__ __align__(16) float4 qs[4096];             // 64 KB
  const int b   = blockIdx.x / K3NB;
  const int hb  = blockIdx.x % K3NB;
  const int hw0 = hb * K3WB;
  const int tid = threadIdx.x;

  const float4* Qg = (const float4*)(Q + (size_t)b*CCH*CCH);
  #pragma unroll
  for(int it=0; it<16; it++){
    const int idx = it*256 + tid;
    const int row = idx >> 5, ch = idx & 31;
    qs[(row<<5) | (ch ^ (row>>3))] = Qg[idx];
  }
  __syncthreads();

  const int tx = tid & 15, ty = tid >> 4;
  const int o0 = tx*8;
  const int hg = ty*4;
  float acc[8][4];
  #pragma unroll
  for(int i=0;i<8;i++){ acc[i][0]=0.f; acc[i][1]=0.f; acc[i][2]=0.f; acc[i][3]=0.f; }

  const unsigned short* Ybb = Ybf + (size_t)b*CCH*HWD + hw0 + hg;
  for(int c4=0;c4<32;c4++){
    float4 yv[4];
    #pragma unroll
    for(int mm=0;mm<4;mm++){
      ushort4 u = *(const ushort4*)(Ybb + (size_t)(4*c4+mm)*HWD);
      yv[mm] = make_float4(bf2f(u.x), bf2f(u.y), bf2f(u.z), bf2f(u.w));
    }
    #pragma unroll
    for(int i=0;i<8;i++){
      const int row = o0 + i;
      const float4 q4 = qs[(row<<5) | (c4 ^ tx)];
      const float ql[4] = {q4.x,q4.y,q4.z,q4.w};
      #pragma unroll
      for(int mm=0;mm<4;mm++){
        acc[i][0]=fmaf(ql[mm],yv[mm].x,acc[i][0]);
        acc[i][1]=fmaf(ql[mm],yv[mm].y,acc[i][1]);
        acc[i][2]=fmaf(ql[mm],yv[mm].z,acc[i][2]);
        acc[i][3]=fmaf(ql[mm],yv[mm].w,acc[i][3]);
      }
    }
  }
  #pragma unroll
  for(int i=0;i<8;i++){
    const float c = cv[b*CCH + o0+i];
    float4 o4 = make_float4(acc[i][0]+c, acc[i][1]+c, acc[i][2]+c, acc[i][3]+c);
    *(float4*)(out + ((size_t)b*CCH + o0+i)*HWD + hw0 + hg) = o4;
  }
}

extern "C" void kernel_launch(void* const* d_in, const int* in_sizes, int n_in,
                              void* d_out, int out_size, void* d_ws, size_t ws_size,
                              hipStream_t stream) {
  const float* x  = (const float*)d_in[0];
  const float* wq = (const float*)d_in[1];
  const float* bq = (const float*)d_in[2];
  const float* wk = (const float*)d_in[3];
  const float* bk = (const float*)d_in[4];
  const float* wv = (const float*)d_in[5];
  const float* bv = (const float*)d_in[6];
  const float* wo = (const float*)d_in[7];
  const float* bo = (const float*)d_in[8];
  float* out = (float*)d_out;
  float* ws  = (float*)d_ws;
  unsigned short* ybf = (unsigned short*)(ws + OFF_YB);

  kA  <<<BB*NWIN, 256, 0, stream>>>(x, ws+OFF_SP);
  kY  <<<BB*CCH, 256, 0, stream>>>(x, ybf, ws+OFF_R);
  k1r <<<128, 256, 0, stream>>>(ws+OFF_SP, ws+OFF_S);
  k2ab<<<64, 256, 0, stream>>>(ws+OFF_S, ws+OFF_R, wq, bq, wk, bk, wv, bv,
                               ws+OFF_M, ws+OFF_AV);
  k2c <<<64, 256, 0, stream>>>(ws+OFF_M, wo, bo, ws+OFF_AV, ws+OFF_Q, ws+OFF_CV);
  k3  <<<BB*K3NB, 256, 0, stream>>>(ws+OFF_Q, ws+OFF_CV, ybf, out);
}

// Round 12
// 149.349 us; speedup vs baseline: 1.7484x; 1.1737x over previous
//
#include <hip/hip_runtime.h>
#include <hip/hip_bf16.h>
#include <cstdint>

#define BB   8
#define CCH  128
#define NND  16
#define HWD  3136      // 56*56
#define LLT  50176     // 16*3136
#define HWB  64        // hw columns per k1 block (R4-proven); 3136 = 49*64
#define NHB  49
#define K3WB 64
#define K3NB 49

// workspace layout (float offsets) — no zero-init required anywhere
#define OFF_SP  0                         // 392 blocks * 10 tiles * 1024 (triangle partials)
#define OFF_S   4014080                   // 8*16384 reconstructed Gram
#define OFF_RP  4145152                   // 8*49*128 rowsum partials
#define OFF_M   4195328
#define OFF_Q   4326400
#define OFF_AV  4457472
#define OFF_CV  4458496

typedef __attribute__((ext_vector_type(8)))  short bf16x8;
typedef __attribute__((ext_vector_type(16))) float f32x16;

__device__ __forceinline__ uint32_t fbits(float f){ union{float f;uint32_t u;}v; v.f=f; return v.u; }
__device__ __forceinline__ float bitsf(uint32_t u){ union{uint32_t u;float f;}v; v.u=u; return v.f; }

#define MFMA32(a,b,c) __builtin_amdgcn_mfma_f32_32x32x16_bf16((a),(b),(c),0,0,0)

// ---------------- k1: SYMMETRIC Gram (lower-triangle tiles) -----------------
// R4-proven staging/loop (HWB=64, dbuf, __syncthreads). Compute: 10 of 16
// tiles (S symmetric); limiting wave 9 MFMA-triplets/ks vs 12.
__global__ __launch_bounds__(256,2) void k1_gram(const float* __restrict__ x,
    float* __restrict__ Sp, float* __restrict__ rp, float* __restrict__ Y)
{
  __shared__ __align__(16) short lds_h[2][8*128*8];   // 2 x 16 KB
  __shared__ __align__(16) short lds_l[2][8*128*8];   // 2 x 16 KB
  const int b   = blockIdx.x / NHB;
  const int hb  = blockIdx.x % NHB;
  const int hw0 = hb * HWB;
  const int tid = threadIdx.x;
  const int lane = tid & 63, w = tid >> 6;            // wave id 0..3
  const int rr  = tid >> 1, h = tid & 1;              // staging: row, half
  const float* xb = x + (size_t)b*CCH*LLT + (size_t)rr*LLT + hw0 + 32*h;

  f32x16 a0, a1, a2;
  #pragma unroll
  for(int e=0;e<16;e++){ a0[e]=0.f; a1[e]=0.f; a2[e]=0.f; }
  float yac[32];
  #pragma unroll
  for(int i=0;i<32;i++) yac[i]=0.f;

  float4 v[8];
  #pragma unroll
  for(int u=0;u<8;u++) v[u] = *(const float4*)(xb + 4*u);   // plane 0

#define SPLIT(bufi)                                                         \
  {                                                                         \
    _Pragma("unroll")                                                       \
    for(int c2=0;c2<4;c2++){                                                \
      int hwd_[4], lwd_[4];                                                 \
      _Pragma("unroll")                                                     \
      for(int q=0;q<2;q++){                                                 \
        const int u = 2*c2+q;                                               \
        const float x0=v[u].x, x1=v[u].y, x2=v[u].z, x3=v[u].w;             \
        const uint32_t b0=fbits(x0),b1=fbits(x1),b2=fbits(x2),b3=fbits(x3); \
        hwd_[2*q+0] = __builtin_amdgcn_perm(b1, b0, 0x07060302u);           \
        hwd_[2*q+1] = __builtin_amdgcn_perm(b3, b2, 0x07060302u);           \
        const float l0 = x0 - bitsf(b0&0xFFFF0000u);                        \
        const float l1 = x1 - bitsf(b1&0xFFFF0000u);                        \
        const float l2 = x2 - bitsf(b2&0xFFFF0000u);                        \
        const float l3 = x3 - bitsf(b3&0xFFFF0000u);                        \
        lwd_[2*q+0] = __builtin_amdgcn_perm(fbits(l1), fbits(l0), 0x07060302u); \
        lwd_[2*q+1] = __builtin_amdgcn_perm(fbits(l3), fbits(l2), 0x07060302u); \
        yac[4*u+0]+=x0; yac[4*u+1]+=x1; yac[4*u+2]+=x2; yac[4*u+3]+=x3;     \
      }                                                                     \
      const int kc = 4*h + c2;                                              \
      *(int4*)&lds_h[bufi][(kc*128 + rr)*8] = make_int4(hwd_[0],hwd_[1],hwd_[2],hwd_[3]); \
      *(int4*)&lds_l[bufi][(kc*128 + rr)*8] = make_int4(lwd_[0],lwd_[1],lwd_[2],lwd_[3]); \
    }                                                                       \
  }

// fragment for row-group g (rows 32g..32g+31), current kcb
#define FR(g)                                                               \
  const bf16x8 f##g##h = *(const bf16x8*)&lds_h[cur][(kcb + 32*g)*8];       \
  const bf16x8 f##g##l = *(const bf16x8*)&lds_l[cur][(kcb + 32*g)*8];

#define TILE(A, gi, gj)                                                     \
  A = MFMA32(f##gi##h, f##gj##h, A);                                        \
  A = MFMA32(f##gi##h, f##gj##l, A);                                        \
  A = MFMA32(f##gi##l, f##gj##h, A);

  SPLIT(0);
  __syncthreads();
  #pragma unroll
  for(int u=0;u<8;u++) v[u] = *(const float4*)(xb + HWD + 4*u);  // plane 1

  for(int n=0;n<NND;n++){
    const int cur = n & 1;
    #pragma unroll
    for(int ks=0;ks<4;ks++){
      const int kcb = (2*ks + (lane>>5))*128 + (lane&31);
      if(w==0){
        FR(0) FR(1)
        TILE(a0,0,0) TILE(a1,1,0) TILE(a2,1,1)
      } else if(w==1){
        FR(0) FR(1) FR(2)
        TILE(a0,2,0) TILE(a1,2,1) TILE(a2,2,2)
      } else if(w==2){
        FR(0) FR(1) FR(3)
        TILE(a0,3,0) TILE(a1,3,1)
      } else {
        FR(2) FR(3)
        TILE(a0,3,2) TILE(a1,3,3)
      }
    }
    if(n+1 < NND){
      SPLIT(cur^1);
      __syncthreads();
      if(n+2 < NND){
        #pragma unroll
        for(int u=0;u<8;u++) v[u] = *(const float4*)(xb + (size_t)(n+2)*HWD + 4*u);
      }
    }
  }
#undef SPLIT
#undef FR
#undef TILE

  // ---- epilogue: Y (fp32 to d_out), rp partial, Sp triangle tiles ----
  #pragma unroll
  for(int u=0;u<8;u++){
    float4 o4 = make_float4(yac[4*u]*0.0625f, yac[4*u+1]*0.0625f,
                            yac[4*u+2]*0.0625f, yac[4*u+3]*0.0625f);
    *(float4*)(Y + ((size_t)b*CCH + rr)*HWD + hw0 + 32*h + 4*u) = o4;
  }
  float p = 0.f;
  #pragma unroll
  for(int i=0;i<32;i++) p += yac[i];
  p += __shfl_xor(p, 1);
  if(h==0) rp[(size_t)(b*NHB+hb)*CCH + rr] = p;

  const int slot0 = (w<2) ? 3*w : 2*w+2;       // {0,3,6,8}
  float* Sb = Sp + ((size_t)blockIdx.x*10 + slot0)*1024;
  const int col = lane & 31, roff = 4*(lane>>5);
#define STORE(A, s)                                                         \
  { _Pragma("unroll")                                                       \
    for(int reg=0;reg<16;reg++){                                            \
      const int row = roff + (reg&3) + 8*(reg>>2);                          \
      Sb[(s)*1024 + row*32 + col] = A[reg];                                 \
    } }
  STORE(a0, 0)
  STORE(a1, 1)
  if(w<2) STORE(a2, 2)
#undef STORE
}

// ---------------- k1rs: reduce 49 windows per tile + mirror -----------------
// grid 80 = b*10 + t. tile t -> (i,j) lower triangle.
__global__ __launch_bounds__(256) void k1rs(const float* __restrict__ Sp,
                                            float* __restrict__ S)
{
  __shared__ float tl[32*33];
  const int b = blockIdx.x/10, t = blockIdx.x%10;
  const int tid = threadIdx.x;
  int i, j;
  if(t<1){ i=0; j=t; } else if(t<3){ i=1; j=t-1; }
  else if(t<6){ i=2; j=t-3; } else { i=3; j=t-6; }

  float4 s = make_float4(0.f,0.f,0.f,0.f);
  const float* p = Sp + ((size_t)(b*NHB)*10 + t)*1024 + 4*tid;
  for(int wdw=0; wdw<NHB; wdw++){
    float4 v = *(const float4*)(p + (size_t)wdw*10240);
    s.x+=v.x; s.y+=v.y; s.z+=v.z; s.w+=v.w;
  }
  const int r = (4*tid) >> 5, c = (4*tid) & 31;
  *(float4*)&S[(size_t)b*CCH*CCH + (size_t)(32*i+r)*CCH + 32*j + c] = s;
  if(i != j){
    tl[r*33 + c+0] = s.x; tl[r*33 + c+1] = s.y;
    tl[r*33 + c+2] = s.z; tl[r*33 + c+3] = s.w;
    __syncthreads();
    const int r2 = tid>>3, c2 = 4*(tid&7);
    float4 o;
    o.x = tl[(c2+0)*33 + r2]; o.y = tl[(c2+1)*33 + r2];
    o.z = tl[(c2+2)*33 + r2]; o.w = tl[(c2+3)*33 + r2];
    *(float4*)&S[(size_t)b*CCH*CCH + (size_t)(32*j+r2)*CCH + 32*i + c2] = o;
  }
}

// ------- k2ab: G = WqSWk^T + bias, softmax -> A (LDS), M = A@Wv, av = A@bv --
__global__ __launch_bounds__(256) void k2ab(const float* __restrict__ S, const float* __restrict__ rp,
    const float* __restrict__ wq, const float* __restrict__ bq,
    const float* __restrict__ wk, const float* __restrict__ bk,
    const float* __restrict__ wv, const float* __restrict__ bv,
    float* __restrict__ M, float* __restrict__ av)
{
  __shared__ __align__(16) float t1[16][132];
  __shared__ float rb_s[CCH];
  __shared__ float wrk_s[CCH];
  __shared__ float wrq_s[16];
  const int b   = blockIdx.x >> 3;
  const int r0  = (blockIdx.x & 7) * 16;
  const int tid = threadIdx.x;
  const float* Sb = S + (size_t)b*CCH*CCH;

  if(tid < CCH){
    float s = 0.f;
    const float* rpb = rp + (size_t)b*NHB*CCH + tid;
    for(int hb=0;hb<NHB;hb++) s += rpb[hb*CCH];
    rb_s[tid] = s;
  }
  __syncthreads();

  if(tid < CCH){
    float s = 0.f;
    for(int m=0;m<CCH;m++) s += wk[(size_t)tid*CCH+m]*rb_s[m];
    wrk_s[tid] = s;
  } else if(tid < CCH+16){
    const int rr2 = tid - CCH;
    float s = 0.f;
    for(int m=0;m<CCH;m++) s += wq[(size_t)(r0+rr2)*CCH+m]*rb_s[m];
    wrq_s[rr2] = s;
  }

  const int rr = tid >> 4;
  const int c0 = (tid & 15) * 8;
  { // T1 = W_q[rows] @ S
    float a8[8] = {0,0,0,0,0,0,0,0};
    const float* wqr = wq + (size_t)(r0+rr)*CCH;
    for(int m4=0;m4<32;m4++){
      float4 w4 = *(const float4*)(wqr + 4*m4);
      const float wl[4] = {w4.x,w4.y,w4.z,w4.w};
      #pragma unroll
      for(int mm=0;mm<4;mm++){
        const int m = 4*m4+mm;
        const float w = wl[mm];
        float4 s0 = *(const float4*)(Sb + (size_t)m*CCH + c0);
        float4 s1 = *(const float4*)(Sb + (size_t)m*CCH + c0 + 4);
        a8[0]=fmaf(w,s0.x,a8[0]); a8[1]=fmaf(w,s0.y,a8[1]);
        a8[2]=fmaf(w,s0.z,a8[2]); a8[3]=fmaf(w,s0.w,a8[3]);
        a8[4]=fmaf(w,s1.x,a8[4]); a8[5]=fmaf(w,s1.y,a8[5]);
        a8[6]=fmaf(w,s1.z,a8[6]); a8[7]=fmaf(w,s1.w,a8[7]);
      }
    }
    #pragma unroll
    for(int j=0;j<8;j++) t1[rr][c0+j] = a8[j];
  }
  __syncthreads();

  const int j0 = c0;
  float g[8] = {0,0,0,0,0,0,0,0};
  for(int c4=0;c4<32;c4++){
    float4 tv = *(const float4*)(&t1[rr][4*c4]);
    #pragma unroll
    for(int jj=0;jj<8;jj++){
      float4 w4 = *(const float4*)(wk + (size_t)(j0+jj)*CCH + 4*c4);
      g[jj]=fmaf(tv.x,w4.x,g[jj]); g[jj]=fmaf(tv.y,w4.y,g[jj]);
      g[jj]=fmaf(tv.z,w4.z,g[jj]); g[jj]=fmaf(tv.w,w4.w,g[jj]);
    }
  }
  const float bqr  = bq[r0+rr];
  const float wrqr = wrq_s[rr];
  #pragma unroll
  for(int jj=0;jj<8;jj++)
    g[jj] += wrqr*bk[j0+jj] + bqr*wrk_s[j0+jj] + (float)LLT*bqr*bk[j0+jj];

  float mx = g[0];
  #pragma unroll
  for(int jj=1;jj<8;jj++) mx = fmaxf(mx, g[jj]);
  #pragma unroll
  for(int s=1;s<16;s<<=1) mx = fmaxf(mx, __shfl_xor(mx, s, 16));
  float ex[8], sum=0.f;
  #pragma unroll
  for(int jj=0;jj<8;jj++){ ex[jj] = expf(g[jj]-mx); sum += ex[jj]; }
  #pragma unroll
  for(int s=1;s<16;s<<=1) sum += __shfl_xor(sum, s, 16);
  const float inv = 1.0f/sum;

  float pa = 0.f;
  #pragma unroll
  for(int jj=0;jj<8;jj++) pa += ex[jj]*inv*bv[j0+jj];
  #pragma unroll
  for(int s=1;s<16;s<<=1) pa += __shfl_xor(pa, s, 16);
  if((tid&15)==0) av[b*CCH + r0+rr] = pa;

  __syncthreads();
  #pragma unroll
  for(int jj=0;jj<8;jj++) t1[rr][j0+jj] = ex[jj]*inv;
  __syncthreads();

  { // M = A @ Wv
    float a8[8] = {0,0,0,0,0,0,0,0};
    for(int k4=0;k4<32;k4++){
      float4 a4 = *(const float4*)(&t1[rr][4*k4]);
      const float al[4] = {a4.x,a4.y,a4.z,a4.w};
      #pragma unroll
      for(int kk=0;kk<4;kk++){
        const int k = 4*k4+kk;
        const float wgt = al[kk];
        float4 v0 = *(const float4*)(wv + (size_t)k*CCH + c0);
        float4 v1 = *(const float4*)(wv + (size_t)k*CCH + c0 + 4);
        a8[0]=fmaf(wgt,v0.x,a8[0]); a8[1]=fmaf(wgt,v0.y,a8[1]);
        a8[2]=fmaf(wgt,v0.z,a8[2]); a8[3]=fmaf(wgt,v0.w,a8[3]);
        a8[4]=fmaf(wgt,v1.x,a8[4]); a8[5]=fmaf(wgt,v1.y,a8[5]);
        a8[6]=fmaf(wgt,v1.z,a8[6]); a8[7]=fmaf(wgt,v1.w,a8[7]);
      }
    }
    float* Mr = M + ((size_t)b*CCH + r0+rr)*CCH + c0;
    *(float4*)(Mr  ) = make_float4(a8[0],a8[1],a8[2],a8[3]);
    *(float4*)(Mr+4) = make_float4(a8[4],a8[5],a8[6],a8[7]);
  }
}

// ---------------- k2c: Q = W_o @ M + I ;  c = W_o av + b_o ------------------
__global__ __launch_bounds__(256) void k2c(const float* __restrict__ M,
    const float* __restrict__ wo, const float* __restrict__ bo,
    const float* __restrict__ av, float* __restrict__ Q, float* __restrict__ cv)
{
  const int b  = blockIdx.x >> 3;
  const int o0 = (blockIdx.x & 7)*16;
  const int tid = threadIdx.x;
  const int rr = tid>>4, c0 = (tid&15)*8;
  const int o  = o0 + rr;
  const float* wor = wo + (size_t)o*CCH;
  const float* Mb  = M + (size_t)b*CCH*CCH;
  float a8[8] = {0,0,0,0,0,0,0,0};
  for(int m4=0;m4<32;m4++){
    float4 w4 = *(const float4*)(wor + 4*m4);
    const float wl[4] = {w4.x,w4.y,w4.z,w4.w};
    #pragma unroll
    for(int mm=0;mm<4;mm++){
      const int m = 4*m4+mm;
      const float w = wl[mm];
      float4 v0 = *(const float4*)(Mb + (size_t)m*CCH + c0);
      float4 v1 = *(const float4*)(Mb + (size_t)m*CCH + c0 + 4);
      a8[0]=fmaf(w,v0.x,a8[0]); a8[1]=fmaf(w,v0.y,a8[1]);
      a8[2]=fmaf(w,v0.z,a8[2]); a8[3]=fmaf(w,v0.w,a8[3]);
      a8[4]=fmaf(w,v1.x,a8[4]); a8[5]=fmaf(w,v1.y,a8[5]);
      a8[6]=fmaf(w,v1.z,a8[6]); a8[7]=fmaf(w,v1.w,a8[7]);
    }
  }
  #pragma unroll
  for(int j=0;j<8;j++) if(o == c0+j) a8[j] += 1.0f;   // +I (residual folded)
  float* Qr = Q + ((size_t)b*CCH + o)*CCH + c0;
  *(float4*)(Qr  ) = make_float4(a8[0],a8[1],a8[2],a8[3]);
  *(float4*)(Qr+4) = make_float4(a8[4],a8[5],a8[6],a8[7]);

  if(tid < 16){
    const int oo = o0 + tid;
    float s = 0.f;
    for(int m=0;m<CCH;m++) s += wo[(size_t)oo*CCH+m]*av[b*CCH+m];
    cv[b*CCH + oo] = s + bo[oo];
  }
}

// ---------------- k3: out = Q @ Y + c  (in place; Q staged in LDS) ----------
__global__ __launch_bounds__(256,2) void k3(const float* __restrict__ Q,
    const float* __restrict__ cv, float* __restrict__ out)
{
  __shared__ __align__(16) float4 qs[4096];             // 64 KB
  const int b   = blockIdx.x / K3NB;
  const int hb  = blockIdx.x % K3NB;
  const int hw0 = hb * K3WB;
  const int tid = threadIdx.x;

  const float4* Qg = (const float4*)(Q + (size_t)b*CCH*CCH);
  #pragma unroll
  for(int it=0; it<16; it++){
    const int idx = it*256 + tid;
    const int row = idx >> 5, ch = idx & 31;
    qs[(row<<5) | (ch ^ (row>>3))] = Qg[idx];
  }
  __syncthreads();

  const int tx = tid & 15, ty = tid >> 4;
  const int o0 = tx*8;
  const int hg = ty*4;
  float acc[8][4];
  #pragma unroll
  for(int i=0;i<8;i++){ acc[i][0]=0.f; acc[i][1]=0.f; acc[i][2]=0.f; acc[i][3]=0.f; }

  const float* Yb = out + (size_t)b*CCH*HWD + hw0 + hg;
  for(int c4=0;c4<32;c4++){
    float4 yv[4];
    #pragma unroll
    for(int mm=0;mm<4;mm++) yv[mm] = *(const float4*)(Yb + (size_t)(4*c4+mm)*HWD);
    #pragma unroll
    for(int i=0;i<8;i++){
      const int row = o0 + i;
      const float4 q4 = qs[(row<<5) | (c4 ^ tx)];
      const float ql[4] = {q4.x,q4.y,q4.z,q4.w};
      #pragma unroll
      for(int mm=0;mm<4;mm++){
        acc[i][0]=fmaf(ql[mm],yv[mm].x,acc[i][0]);
        acc[i][1]=fmaf(ql[mm],yv[mm].y,acc[i][1]);
        acc[i][2]=fmaf(ql[mm],yv[mm].z,acc[i][2]);
        acc[i][3]=fmaf(ql[mm],yv[mm].w,acc[i][3]);
      }
    }
  }
  __syncthreads();                          // all Y reads done before overwrite
  #pragma unroll
  for(int i=0;i<8;i++){
    const float c = cv[b*CCH + o0+i];
    float4 o4 = make_float4(acc[i][0]+c, acc[i][1]+c, acc[i][2]+c, acc[i][3]+c);
    *(float4*)(out + ((size_t)b*CCH + o0+i)*HWD + hw0 + hg) = o4;
  }
}

extern "C" void kernel_launch(void* const* d_in, const int* in_sizes, int n_in,
                              void* d_out, int out_size, void* d_ws, size_t ws_size,
                              hipStream_t stream) {
  const float* x  = (const float*)d_in[0];
  const float* wq = (const float*)d_in[1];
  const float* bq = (const float*)d_in[2];
  const float* wk = (const float*)d_in[3];
  const float* bk = (const float*)d_in[4];
  const float* wv = (const float*)d_in[5];
  const float* bv = (const float*)d_in[6];
  const float* wo = (const float*)d_in[7];
  const float* bo = (const float*)d_in[8];
  float* out = (float*)d_out;
  float* ws  = (float*)d_ws;

  k1_gram<<<BB*NHB, 256, 0, stream>>>(x, ws+OFF_SP, ws+OFF_RP, out);
  k1rs  <<<80, 256, 0, stream>>>(ws+OFF_SP, ws+OFF_S);
  k2ab  <<<64, 256, 0, stream>>>(ws+OFF_S, ws+OFF_RP, wq, bq, wk, bk, wv, bv,
                                 ws+OFF_M, ws+OFF_AV);
  k2c   <<<64, 256, 0, stream>>>(ws+OFF_M, wo, bo, ws+OFF_AV, ws+OFF_Q, ws+OFF_CV);
  k3    <<<BB*K3NB, 256, 0, stream>>>(ws+OFF_Q, ws+OFF_CV, out);
}